// Round 1
// baseline (4702.318 us; speedup 1.0000x reference)
//
#include <hip/hip_runtime.h>
#include <hip/hip_bf16.h>
#include <math.h>

// ---------------------------------------------------------------------------
// MambaBlock (bimamba v2), fp32 baseline.
// Shapes: B=4, L=1024, D_MODEL=768, D_INNER=1536, DT_RANK=48, D_STATE=16.
// Per branch (r, i):
//   hn = LayerNorm(h) ; xz = hn @ in_w.T  [4096 x 3072]
//   per dir (fwd, bwd on reversed time):
//     xc   = silu(causal_dwconv(x))              [4096 x 1536]
//     xdbl = xc @ xp_w.T                          [4096 x 80]
//     dt   = softplus(xdbl[:, :48] @ dtp_w.T + b) [4096 x 1536]
//     y    = selective_scan(xc, dt, A, B, C) + xc*Dp  -> accumulate into g
//   g *= silu(z) ; out = g @ out_w.T
// ---------------------------------------------------------------------------

#define BB 4
#define LL 1024
#define DM 768
#define DI 1536
#define RK 48
#define NS 16

__device__ __forceinline__ float siluf(float x) {
    return x / (1.f + __expf(-x));
}
__device__ __forceinline__ float softplusf(float x) {
    return (x > 20.f) ? x : log1pf(__expf(x));
}

// ---------------- LayerNorm: one block per row of 768 ----------------------
__global__ __launch_bounds__(256)
void ln_kernel(const float* __restrict__ h, const float* __restrict__ w,
               const float* __restrict__ bvec, float* __restrict__ out)
{
    int row = blockIdx.x;                 // 0 .. B*L-1
    const float* x = h + (size_t)row * DM;
    int tid = threadIdx.x;
    float v[3];
    float s = 0.f, s2 = 0.f;
#pragma unroll
    for (int j = 0; j < 3; ++j) {
        v[j] = x[tid + j * 256];
        s += v[j];
        s2 += v[j] * v[j];
    }
#pragma unroll
    for (int off = 32; off > 0; off >>= 1) {
        s += __shfl_down(s, off);
        s2 += __shfl_down(s2, off);
    }
    __shared__ float sw[4], sw2[4], stat[2];
    int wid = tid >> 6;
    if ((tid & 63) == 0) { sw[wid] = s; sw2[wid] = s2; }
    __syncthreads();
    if (tid == 0) {
        float a = sw[0] + sw[1] + sw[2] + sw[3];
        float a2 = sw2[0] + sw2[1] + sw2[2] + sw2[3];
        float mu = a * (1.f / DM);
        float var = a2 * (1.f / DM) - mu * mu;
        stat[0] = mu;
        stat[1] = rsqrtf(var + 1e-5f);
    }
    __syncthreads();
    float mu = stat[0], rs = stat[1];
    float* o = out + (size_t)row * DM;
#pragma unroll
    for (int j = 0; j < 3; ++j) {
        int i = tid + j * 256;
        o[i] = (v[j] - mu) * rs * w[i] + bvec[i];
    }
}

// ---------------- fp32 tiled GEMM: C = act(A @ B^T + bias) ------------------
// A: [M,K] row-major with row stride lda ; B: [N,K] row stride ldb.
// ACT: 0 = none, 1 = +bias then softplus.
template <int BM, int BN, int BK, int TM, int TN, int ACT>
__global__ __launch_bounds__(256)
void gemm_tn(const float* __restrict__ A, int lda,
             const float* __restrict__ B, int ldb,
             const float* __restrict__ bias,
             float* __restrict__ C, int ldc, int K)
{
    constexpr int TX = BN / TN;
    constexpr int TY = BM / TM;
    static_assert(TX * TY == 256, "thread count must be 256");
    __shared__ float As[BK][BM + 4];
    __shared__ float Bs[BK][BN + 4];

    int tid = threadIdx.x;
    int tx = tid % TX, ty = tid / TX;
    int m0 = blockIdx.y * BM, n0 = blockIdx.x * BN;

    float acc[TM][TN];
#pragma unroll
    for (int i = 0; i < TM; ++i)
#pragma unroll
        for (int j = 0; j < TN; ++j) acc[i][j] = 0.f;

    for (int kt = 0; kt < K; kt += BK) {
#pragma unroll
        for (int i = tid; i < BM * BK; i += 256) {
            int m = i / BK, k = i % BK;
            As[k][m] = A[(size_t)(m0 + m) * lda + kt + k];
        }
#pragma unroll
        for (int i = tid; i < BN * BK; i += 256) {
            int n = i / BK, k = i % BK;
            Bs[k][n] = B[(size_t)(n0 + n) * ldb + kt + k];
        }
        __syncthreads();
#pragma unroll
        for (int kk = 0; kk < BK; ++kk) {
            float a[TM], b[TN];
#pragma unroll
            for (int i = 0; i < TM; ++i) a[i] = As[kk][ty * TM + i];
#pragma unroll
            for (int j = 0; j < TN; ++j) b[j] = Bs[kk][tx * TN + j];
#pragma unroll
            for (int i = 0; i < TM; ++i)
#pragma unroll
                for (int j = 0; j < TN; ++j) acc[i][j] += a[i] * b[j];
        }
        __syncthreads();
    }

#pragma unroll
    for (int i = 0; i < TM; ++i) {
#pragma unroll
        for (int j = 0; j < TN; ++j) {
            int m = m0 + ty * TM + i, n = n0 + tx * TN + j;
            float v = acc[i][j];
            if (ACT == 1) v = softplusf(v + bias[n]);
            C[(size_t)m * ldc + n] = v;
        }
    }
}

// ---------------- causal depthwise conv (k=4) + silu ------------------------
// rev=0: xc[b,t,d] from x[b, t-3..t, d]
// rev=1: operates on time-reversed x, writes reversed-order xc.
__global__ __launch_bounds__(256)
void conv_silu_kernel(const float* __restrict__ xz, const float* __restrict__ w,
                      const float* __restrict__ bias, float* __restrict__ xc,
                      int rev)
{
    int gid = blockIdx.x * 256 + threadIdx.x;   // over B*L*DI
    int d = gid % DI;
    int bt = gid / DI;
    int t = bt % LL;
    int b = bt / LL;
    float acc = bias[d];
#pragma unroll
    for (int i = 0; i < 4; ++i) {
        int tt = t - 3 + i;
        if (tt >= 0) {
            int st = rev ? (LL - 1 - tt) : tt;
            acc += xz[((size_t)(b * LL + st)) * (2 * DI) + d] * w[d * 4 + i];
        }
    }
    xc[gid] = siluf(acc);
}

// ---------------- selective scan -------------------------------------------
// one lane per (b, d, n); 16 lanes (n=0..15) cooperate per channel.
// rev=0: g[b,t,d]  = y ;  rev=1: g[b,L-1-t,d] += y  (t is processing order)
__global__ __launch_bounds__(256)
void scan_kernel(const float* __restrict__ dt, const float* __restrict__ u,
                 const float* __restrict__ xdbl, const float* __restrict__ A_log,
                 const float* __restrict__ Dp, float* __restrict__ g, int rev)
{
    int gid = blockIdx.x * 256 + threadIdx.x;   // over B*DI*NS
    int n = gid & 15;
    int c = gid >> 4;
    int d = c % DI;
    int b = c / DI;

    float Av = -expf(A_log[d * NS + n]);
    float Dpv = Dp[d];
    float h = 0.f;

    size_t base = ((size_t)b * LL) * DI + d;
    size_t xb = ((size_t)b * LL) * 80;

    // software pipeline: current values + prefetch next step
    float dtv = dt[base];
    float uv = u[base];
    float Bv = xdbl[xb + 48 + n];
    float Cv = xdbl[xb + 64 + n];

    for (int t = 0; t < LL; ++t) {
        float dtn = 0.f, un = 0.f, Bn = 0.f, Cn = 0.f;
        if (t + 1 < LL) {
            size_t i2 = base + (size_t)(t + 1) * DI;
            dtn = dt[i2];
            un = u[i2];
            size_t x2 = xb + (size_t)(t + 1) * 80;
            Bn = xdbl[x2 + 48 + n];
            Cn = xdbl[x2 + 64 + n];
        }
        float dA = __expf(dtv * Av);
        h = dA * h + (dtv * uv) * Bv;
        float yp = h * Cv;
        yp += __shfl_xor(yp, 8);
        yp += __shfl_xor(yp, 4);
        yp += __shfl_xor(yp, 2);
        yp += __shfl_xor(yp, 1);
        if (n == 0) {
            int ot = rev ? (LL - 1 - t) : t;
            size_t oi = ((size_t)b * LL + ot) * DI + d;
            float val = yp + uv * Dpv;
            if (rev) g[oi] += val;
            else     g[oi] = val;
        }
        dtv = dtn; uv = un; Bv = Bn; Cv = Cn;
    }
}

// ---------------- gate: g *= silu(z) ---------------------------------------
__global__ __launch_bounds__(256)
void gate_kernel(float* __restrict__ g, const float* __restrict__ xz)
{
    int gid = blockIdx.x * 256 + threadIdx.x;   // over B*L*DI
    int d = gid % DI;
    int bt = gid / DI;
    float z = xz[(size_t)bt * (2 * DI) + DI + d];
    g[gid] *= siluf(z);
}

// ---------------------------------------------------------------------------
extern "C" void kernel_launch(void* const* d_in, const int* in_sizes, int n_in,
                              void* d_out, int out_size, void* d_ws, size_t ws_size,
                              hipStream_t stream)
{
    const float* h_r        = (const float*)d_in[0];
    const float* h_i        = (const float*)d_in[1];
    const float* ln_w       = (const float*)d_in[2];
    const float* ln_b       = (const float*)d_in[3];
    const float* in_w       = (const float*)d_in[4];
    const float* conv_w     = (const float*)d_in[5];
    const float* conv_bias  = (const float*)d_in[6];
    const float* xp_w       = (const float*)d_in[7];
    const float* dtp_w      = (const float*)d_in[8];
    const float* dtp_bias   = (const float*)d_in[9];
    const float* A_log      = (const float*)d_in[10];
    const float* D_p        = (const float*)d_in[11];
    const float* conv_w_b   = (const float*)d_in[12];
    const float* conv_bias_b= (const float*)d_in[13];
    const float* xp_w_b     = (const float*)d_in[14];
    const float* dtp_w_b    = (const float*)d_in[15];
    const float* dtp_bias_b = (const float*)d_in[16];
    const float* A_b_log    = (const float*)d_in[17];
    const float* D_b        = (const float*)d_in[18];
    const float* out_w      = (const float*)d_in[19];
    float* out = (float*)d_out;

    // workspace layout (floats): g (6.29M, hn aliases its head), xz (12.58M),
    // xc (6.29M), dt (6.29M), xdbl (0.33M)  -> ~127 MB
    float* ws   = (float*)d_ws;
    float* g    = ws;
    float* hn   = ws;                        // dead before g is written
    float* xz   = ws + (size_t)BB * LL * DI; // 6,291,456
    float* xc   = xz + (size_t)BB * LL * 2 * DI;
    float* dtb  = xc + (size_t)BB * LL * DI;
    float* xdbl = dtb + (size_t)BB * LL * DI;

    const size_t out_stride = (size_t)BB * LL * DM;

    for (int br = 0; br < 2; ++br) {
        const float* h = br ? h_i : h_r;

        ln_kernel<<<BB * LL, 256, 0, stream>>>(h, ln_w + br * DM, ln_b + br * DM, hn);

        // xz = hn @ in_w.T   [4096 x 3072], K=768
        gemm_tn<128, 128, 8, 8, 8, 0><<<dim3((2 * DI) / 128, (BB * LL) / 128), 256, 0, stream>>>(
            hn, DM, in_w + (size_t)br * 2 * DI * DM, DM, nullptr, xz, 2 * DI, DM);

        for (int dir = 0; dir < 2; ++dir) {
            const float* cw = (dir ? conv_w_b : conv_w) + (size_t)br * DI * 4;
            const float* cb = (dir ? conv_bias_b : conv_bias) + (size_t)br * DI;
            const float* xw = (dir ? xp_w_b : xp_w) + (size_t)br * 80 * DI;
            const float* dw = (dir ? dtp_w_b : dtp_w) + (size_t)br * DI * RK;
            const float* db = (dir ? dtp_bias_b : dtp_bias) + (size_t)br * DI;
            const float* al = (dir ? A_b_log : A_log) + (size_t)br * DI * NS;
            const float* dp = (dir ? D_b : D_p) + (size_t)br * DI;

            conv_silu_kernel<<<(BB * LL * DI) / 256, 256, 0, stream>>>(xz, cw, cb, xc, dir);

            // xdbl = xc @ xp_w.T   [4096 x 80], K=1536
            gemm_tn<32, 80, 16, 2, 5, 0><<<dim3(1, (BB * LL) / 32), 256, 0, stream>>>(
                xc, DI, xw, DI, nullptr, xdbl, 80, DI);

            // dt = softplus(xdbl[:, :48] @ dtp_w.T + bias)   [4096 x 1536], K=48
            gemm_tn<128, 128, 8, 8, 8, 1><<<dim3(DI / 128, (BB * LL) / 128), 256, 0, stream>>>(
                xdbl, 80, dw, RK, db, dtb, DI, RK);

            scan_kernel<<<(BB * DI * NS) / 256, 256, 0, stream>>>(
                dtb, xc, xdbl, al, dp, g, dir);
        }

        gate_kernel<<<(BB * LL * DI) / 256, 256, 0, stream>>>(g, xz);

        // out = g @ out_w.T   [4096 x 768], K=1536
        gemm_tn<128, 128, 8, 8, 8, 0><<<dim3(DM / 128, (BB * LL) / 128), 256, 0, stream>>>(
            g, DI, out_w + (size_t)br * DM * DI, DI, nullptr,
            out + br * out_stride, DM, DI);
    }
}

// Round 2
// 2274.671 us; speedup vs baseline: 2.0673x; 2.0673x over previous
//
#include <hip/hip_runtime.h>
#include <hip/hip_bf16.h>
#include <math.h>

// ---------------------------------------------------------------------------
// MambaBlock (bimamba v2). Round 1:
//  - chunked 2-pass parallel selective scan (16 chunks of 64; 16x parallelism)
//  - bf16 MFMA (16x16x32) GEMMs for in_proj / out_proj
//  - fp32 tiled GEMMs kept for x_proj (K=1536, N=80) and dt_proj (K=48)
// Shapes: B=4, L=1024, D_MODEL=768, D_INNER=1536, DT_RANK=48, D_STATE=16.
// ---------------------------------------------------------------------------

#define BB 4
#define LL 1024
#define DM 768
#define DI 1536
#define RK 48
#define NS 16
#define CH 16          // scan chunks
#define CLEN 64        // LL / CH

typedef __attribute__((ext_vector_type(8))) short bf16x8;
typedef __attribute__((ext_vector_type(4))) float f32x4;

__device__ __forceinline__ float siluf(float x) {
    return x / (1.f + __expf(-x));
}
__device__ __forceinline__ float softplusf(float x) {
    return (x > 20.f) ? x : log1pf(__expf(x));
}
__device__ __forceinline__ unsigned short f2bf(float x) {
    __hip_bfloat16 h = __float2bfloat16(x);
    return *(unsigned short*)&h;
}

// ---------------- LayerNorm: one block per row of 768, bf16 out ------------
__global__ __launch_bounds__(256)
void ln_kernel(const float* __restrict__ h, const float* __restrict__ w,
               const float* __restrict__ bvec, unsigned short* __restrict__ out)
{
    int row = blockIdx.x;                 // 0 .. B*L-1
    const float* x = h + (size_t)row * DM;
    int tid = threadIdx.x;
    float v[3];
    float s = 0.f, s2 = 0.f;
#pragma unroll
    for (int j = 0; j < 3; ++j) {
        v[j] = x[tid + j * 256];
        s += v[j];
        s2 += v[j] * v[j];
    }
#pragma unroll
    for (int off = 32; off > 0; off >>= 1) {
        s += __shfl_down(s, off);
        s2 += __shfl_down(s2, off);
    }
    __shared__ float sw[4], sw2[4], stat[2];
    int wid = tid >> 6;
    if ((tid & 63) == 0) { sw[wid] = s; sw2[wid] = s2; }
    __syncthreads();
    if (tid == 0) {
        float a = sw[0] + sw[1] + sw[2] + sw[3];
        float a2 = sw2[0] + sw2[1] + sw2[2] + sw2[3];
        float mu = a * (1.f / DM);
        float var = a2 * (1.f / DM) - mu * mu;
        stat[0] = mu;
        stat[1] = rsqrtf(var + 1e-5f);
    }
    __syncthreads();
    float mu = stat[0], rs = stat[1];
    unsigned short* o = out + (size_t)row * DM;
#pragma unroll
    for (int j = 0; j < 3; ++j) {
        int i = tid + j * 256;
        o[i] = f2bf((v[j] - mu) * rs * w[i] + bvec[i]);
    }
}

// ---------------- fp32 -> bf16 cast (4 elems / thread) ---------------------
__global__ __launch_bounds__(256)
void cast_kernel(const float* __restrict__ x, unsigned short* __restrict__ y)
{
    int i = (blockIdx.x * 256 + threadIdx.x) * 4;
    float4 v = *(const float4*)(x + i);
    y[i + 0] = f2bf(v.x);
    y[i + 1] = f2bf(v.y);
    y[i + 2] = f2bf(v.z);
    y[i + 3] = f2bf(v.w);
}

// ---------------- bf16 MFMA GEMM: C = A @ B^T (fp32 out) -------------------
// A: [M,K] bf16 row-major (lda), B: [N,K] bf16 row-major (ldb).
// 128x128 tile, BK=32, 4 waves each computing a 64x64 quadrant.
__global__ __launch_bounds__(256)
void gemm_mfma_bt(const unsigned short* __restrict__ A, int lda,
                  const unsigned short* __restrict__ B, int ldb,
                  float* __restrict__ C, int ldc, int K)
{
    __shared__ unsigned short As[128 * 32];
    __shared__ unsigned short Bs[128 * 32];
    int tid = threadIdx.x;
    int wave = tid >> 6, lane = tid & 63;
    int wm = wave & 1, wn = wave >> 1;      // 2x2 wave grid
    int quad = lane >> 4, lr = lane & 15;
    int m0 = blockIdx.y * 128, n0 = blockIdx.x * 128;

    f32x4 acc[4][4];
#pragma unroll
    for (int i = 0; i < 4; ++i)
#pragma unroll
        for (int j = 0; j < 4; ++j) acc[i][j] = (f32x4){0.f, 0.f, 0.f, 0.f};

    for (int kt = 0; kt < K; kt += 32) {
        // stage 128x32 of A and B: 512 8-elem (16B) loads, 2 per thread each
#pragma unroll
        for (int i = 0; i < 2; ++i) {
            int idx = tid + i * 256;               // 0..511
            int row = idx >> 2, col = (idx & 3) * 8;
            *(float4*)(&As[row * 32 + col]) =
                *(const float4*)(A + (size_t)(m0 + row) * lda + kt + col);
            *(float4*)(&Bs[row * 32 + col]) =
                *(const float4*)(B + (size_t)(n0 + row) * ldb + kt + col);
        }
        __syncthreads();

        bf16x8 af[4], bf[4];
#pragma unroll
        for (int mt = 0; mt < 4; ++mt)
            af[mt] = *(const bf16x8*)(&As[(wm * 64 + mt * 16 + lr) * 32 + quad * 8]);
#pragma unroll
        for (int nt = 0; nt < 4; ++nt)
            bf[nt] = *(const bf16x8*)(&Bs[(wn * 64 + nt * 16 + lr) * 32 + quad * 8]);
#pragma unroll
        for (int mt = 0; mt < 4; ++mt)
#pragma unroll
            for (int nt = 0; nt < 4; ++nt)
                acc[mt][nt] = __builtin_amdgcn_mfma_f32_16x16x32_bf16(
                    af[mt], bf[nt], acc[mt][nt], 0, 0, 0);
        __syncthreads();
    }

    // epilogue: D lane mapping col = lane&15, row = quad*4 + reg
#pragma unroll
    for (int mt = 0; mt < 4; ++mt) {
#pragma unroll
        for (int nt = 0; nt < 4; ++nt) {
#pragma unroll
            for (int e = 0; e < 4; ++e) {
                int m = m0 + wm * 64 + mt * 16 + quad * 4 + e;
                int n = n0 + wn * 64 + nt * 16 + lr;
                C[(size_t)m * ldc + n] = acc[mt][nt][e];
            }
        }
    }
}

// ---------------- fp32 tiled GEMM: C = act(A @ B^T + bias) ------------------
template <int BM, int BN, int BK, int TM, int TN, int ACT>
__global__ __launch_bounds__(256)
void gemm_tn(const float* __restrict__ A, int lda,
             const float* __restrict__ B, int ldb,
             const float* __restrict__ bias,
             float* __restrict__ C, int ldc, int K)
{
    constexpr int TX = BN / TN;
    constexpr int TY = BM / TM;
    static_assert(TX * TY == 256, "thread count must be 256");
    __shared__ float As[BK][BM + 4];
    __shared__ float Bs[BK][BN + 4];

    int tid = threadIdx.x;
    int tx = tid % TX, ty = tid / TX;
    int m0 = blockIdx.y * BM, n0 = blockIdx.x * BN;

    float acc[TM][TN];
#pragma unroll
    for (int i = 0; i < TM; ++i)
#pragma unroll
        for (int j = 0; j < TN; ++j) acc[i][j] = 0.f;

    for (int kt = 0; kt < K; kt += BK) {
#pragma unroll
        for (int i = tid; i < BM * BK; i += 256) {
            int m = i / BK, k = i % BK;
            As[k][m] = A[(size_t)(m0 + m) * lda + kt + k];
        }
#pragma unroll
        for (int i = tid; i < BN * BK; i += 256) {
            int n = i / BK, k = i % BK;
            Bs[k][n] = B[(size_t)(n0 + n) * ldb + kt + k];
        }
        __syncthreads();
#pragma unroll
        for (int kk = 0; kk < BK; ++kk) {
            float a[TM], b[TN];
#pragma unroll
            for (int i = 0; i < TM; ++i) a[i] = As[kk][ty * TM + i];
#pragma unroll
            for (int j = 0; j < TN; ++j) b[j] = Bs[kk][tx * TN + j];
#pragma unroll
            for (int i = 0; i < TM; ++i)
#pragma unroll
                for (int j = 0; j < TN; ++j) acc[i][j] += a[i] * b[j];
        }
        __syncthreads();
    }

#pragma unroll
    for (int i = 0; i < TM; ++i) {
#pragma unroll
        for (int j = 0; j < TN; ++j) {
            int m = m0 + ty * TM + i, n = n0 + tx * TN + j;
            float v = acc[i][j];
            if (ACT == 1) v = softplusf(v + bias[n]);
            C[(size_t)m * ldc + n] = v;
        }
    }
}

// ---------------- causal depthwise conv (k=4) + silu ------------------------
__global__ __launch_bounds__(256)
void conv_silu_kernel(const float* __restrict__ xz, const float* __restrict__ w,
                      const float* __restrict__ bias, float* __restrict__ xc,
                      int rev)
{
    int gid = blockIdx.x * 256 + threadIdx.x;   // over B*L*DI
    int d = gid % DI;
    int bt = gid / DI;
    int t = bt % LL;
    int b = bt / LL;
    float acc = bias[d];
#pragma unroll
    for (int i = 0; i < 4; ++i) {
        int tt = t - 3 + i;
        if (tt >= 0) {
            int st = rev ? (LL - 1 - tt) : tt;
            acc += xz[((size_t)(b * LL + st)) * (2 * DI) + d] * w[d * 4 + i];
        }
    }
    xc[gid] = siluf(acc);
}

// ---------------- selective scan, pass 1: per-chunk (p, q) ------------------
// lane = (b, d, n); blockIdx.y = chunk. h_t = dA_t h_{t-1} + db_t within chunk
// summarizes to h_end = p * h_start + q.
__global__ __launch_bounds__(256)
void scan_p1(const float* __restrict__ dt, const float* __restrict__ u,
             const float* __restrict__ xdbl, const float* __restrict__ A_log,
             float2* __restrict__ PQ)
{
    int gid = blockIdx.x * 256 + threadIdx.x;   // over B*DI*NS
    int c = blockIdx.y;
    int n = gid & 15;
    int dch = gid >> 4;
    int d = dch % DI, b = dch / DI;

    float Av = -expf(A_log[d * NS + n]);
    size_t base = ((size_t)b * LL + c * CLEN) * DI + d;
    size_t xb = ((size_t)b * LL + c * CLEN) * 80;

    float p = 1.f, q = 0.f;
    for (int t = 0; t < CLEN; ++t) {
        float dtv = dt[base + (size_t)t * DI];
        float uv = u[base + (size_t)t * DI];
        float Bv = xdbl[xb + t * 80 + 48 + n];
        float dA = __expf(dtv * Av);
        q = dA * q + (dtv * uv) * Bv;
        p *= dA;
    }
    PQ[(size_t)gid * CH + c] = make_float2(p, q);
}

// ---------------- selective scan, pass 2: replay with true h0 ---------------
__global__ __launch_bounds__(256)
void scan_p2(const float* __restrict__ dt, const float* __restrict__ u,
             const float* __restrict__ xdbl, const float* __restrict__ A_log,
             const float* __restrict__ Dp, const float2* __restrict__ PQ,
             float* __restrict__ g, int rev)
{
    int gid = blockIdx.x * 256 + threadIdx.x;
    int c = blockIdx.y;
    int n = gid & 15;
    int dch = gid >> 4;
    int d = dch % DI, b = dch / DI;

    float Av = -expf(A_log[d * NS + n]);
    float Dpv = Dp[d];

    // compose chunk summaries 0..c-1 to get this chunk's initial state
    float h = 0.f;
    const float2* pq = PQ + (size_t)gid * CH;
    for (int cc = 0; cc < c; ++cc) {
        float2 s = pq[cc];
        h = s.x * h + s.y;
    }

    size_t base = ((size_t)b * LL + c * CLEN) * DI + d;
    size_t xb = ((size_t)b * LL + c * CLEN) * 80;

    for (int t = 0; t < CLEN; ++t) {
        float dtv = dt[base + (size_t)t * DI];
        float uv = u[base + (size_t)t * DI];
        float Bv = xdbl[xb + t * 80 + 48 + n];
        float Cv = xdbl[xb + t * 80 + 64 + n];
        float dA = __expf(dtv * Av);
        h = dA * h + (dtv * uv) * Bv;
        float yp = h * Cv;
        yp += __shfl_xor(yp, 8);
        yp += __shfl_xor(yp, 4);
        yp += __shfl_xor(yp, 2);
        yp += __shfl_xor(yp, 1);
        if (n == 0) {
            int tt = c * CLEN + t;
            int ot = rev ? (LL - 1 - tt) : tt;
            size_t oi = ((size_t)b * LL + ot) * DI + d;
            float val = yp + uv * Dpv;
            if (rev) g[oi] += val;
            else     g[oi] = val;
        }
    }
}

// ---------------- gate: gb = bf16(g * silu(z)) ------------------------------
__global__ __launch_bounds__(256)
void gate_kernel(const float* __restrict__ g, const float* __restrict__ xz,
                 unsigned short* __restrict__ gb)
{
    int gid = blockIdx.x * 256 + threadIdx.x;   // over B*L*DI
    int d = gid % DI;
    int bt = gid / DI;
    float z = xz[(size_t)bt * (2 * DI) + DI + d];
    gb[gid] = f2bf(g[gid] * siluf(z));
}

// ---------------------------------------------------------------------------
extern "C" void kernel_launch(void* const* d_in, const int* in_sizes, int n_in,
                              void* d_out, int out_size, void* d_ws, size_t ws_size,
                              hipStream_t stream)
{
    const float* h_r        = (const float*)d_in[0];
    const float* h_i        = (const float*)d_in[1];
    const float* ln_w       = (const float*)d_in[2];
    const float* ln_b       = (const float*)d_in[3];
    const float* in_w       = (const float*)d_in[4];
    const float* conv_w     = (const float*)d_in[5];
    const float* conv_bias  = (const float*)d_in[6];
    const float* xp_w       = (const float*)d_in[7];
    const float* dtp_w      = (const float*)d_in[8];
    const float* dtp_bias   = (const float*)d_in[9];
    const float* A_log      = (const float*)d_in[10];
    const float* D_p        = (const float*)d_in[11];
    const float* conv_w_b   = (const float*)d_in[12];
    const float* conv_bias_b= (const float*)d_in[13];
    const float* xp_w_b     = (const float*)d_in[14];
    const float* dtp_w_b    = (const float*)d_in[15];
    const float* dtp_bias_b = (const float*)d_in[16];
    const float* A_b_log    = (const float*)d_in[17];
    const float* D_b        = (const float*)d_in[18];
    const float* out_w      = (const float*)d_in[19];
    float* out = (float*)d_out;

    // workspace layout
    float*  ws   = (float*)d_ws;
    float*  g    = ws;                              // 6,291,456 f
    float*  xz   = g + (size_t)BB * LL * DI;        // 12,582,912 f
    float*  xc   = xz + (size_t)BB * LL * 2 * DI;   // 6,291,456 f
    float*  dtb  = xc + (size_t)BB * LL * DI;       // 6,291,456 f
    float*  xdbl = dtb + (size_t)BB * LL * DI;      // 327,680 f
    float2* PQ   = (float2*)(xdbl + (size_t)BB * LL * 80);        // 1,572,864 f2
    unsigned short* gb  = (unsigned short*)(PQ + (size_t)BB * DI * NS * CH); // 6,291,456 us
    unsigned short* hnb = gb;                       // alias: dead before gate
    unsigned short* wbi = gb + (size_t)BB * LL * DI;   // 2,359,296 us
    unsigned short* wbo = wbi + (size_t)2 * DI * DM;   // 1,179,648 us

    const size_t out_stride = (size_t)BB * LL * DM;

    for (int br = 0; br < 2; ++br) {
        const float* h = br ? h_i : h_r;

        ln_kernel<<<BB * LL, 256, 0, stream>>>(h, ln_w + br * DM, ln_b + br * DM, hnb);

        // cast this branch's big weights to bf16
        cast_kernel<<<(2 * DI * DM) / 1024, 256, 0, stream>>>(
            in_w + (size_t)br * 2 * DI * DM, wbi);
        cast_kernel<<<(DM * DI) / 1024, 256, 0, stream>>>(
            out_w + (size_t)br * DM * DI, wbo);

        // xz = hn @ in_w.T   [4096 x 3072], K=768  (bf16 MFMA)
        gemm_mfma_bt<<<dim3((2 * DI) / 128, (BB * LL) / 128), 256, 0, stream>>>(
            hnb, DM, wbi, DM, xz, 2 * DI, DM);

        for (int dir = 0; dir < 2; ++dir) {
            const float* cw = (dir ? conv_w_b : conv_w) + (size_t)br * DI * 4;
            const float* cb = (dir ? conv_bias_b : conv_bias) + (size_t)br * DI;
            const float* xw = (dir ? xp_w_b : xp_w) + (size_t)br * 80 * DI;
            const float* dw = (dir ? dtp_w_b : dtp_w) + (size_t)br * DI * RK;
            const float* db = (dir ? dtp_bias_b : dtp_bias) + (size_t)br * DI;
            const float* al = (dir ? A_b_log : A_log) + (size_t)br * DI * NS;
            const float* dp = (dir ? D_b : D_p) + (size_t)br * DI;

            conv_silu_kernel<<<(BB * LL * DI) / 256, 256, 0, stream>>>(xz, cw, cb, xc, dir);

            // xdbl = xc @ xp_w.T   [4096 x 80], K=1536  (fp32)
            gemm_tn<32, 80, 16, 2, 5, 0><<<dim3(1, (BB * LL) / 32), 256, 0, stream>>>(
                xc, DI, xw, DI, nullptr, xdbl, 80, DI);

            // dt = softplus(xdbl[:, :48] @ dtp_w.T + bias)   [4096 x 1536], K=48 (fp32)
            gemm_tn<128, 128, 8, 8, 8, 1><<<dim3(DI / 128, (BB * LL) / 128), 256, 0, stream>>>(
                xdbl, 80, dw, RK, db, dtb, DI, RK);

            // chunked parallel scan
            scan_p1<<<dim3((BB * DI * NS) / 256, CH), 256, 0, stream>>>(
                dtb, xc, xdbl, al, PQ);
            scan_p2<<<dim3((BB * DI * NS) / 256, CH), 256, 0, stream>>>(
                dtb, xc, xdbl, al, dp, PQ, g, dir);
        }

        gate_kernel<<<(BB * LL * DI) / 256, 256, 0, stream>>>(g, xz, gb);

        // out = g @ out_w.T   [4096 x 768], K=1536  (bf16 MFMA)
        gemm_mfma_bt<<<dim3(DM / 128, (BB * LL) / 128), 256, 0, stream>>>(
            gb, DI, wbo, DI, out + br * out_stride, DM, DI);
    }
}

// Round 3
// 1582.356 us; speedup vs baseline: 2.9717x; 1.4375x over previous
//
#include <hip/hip_runtime.h>
#include <hip/hip_bf16.h>
#include <math.h>

// ---------------------------------------------------------------------------
// MambaBlock (bimamba v2). Round 2:
//  - x_proj GEMM rewritten as split-K (8 chunks) fp32 partial GEMM + reduce:
//    512 blocks @ 19.5KB LDS (was 128 blocks, 5.9% occupancy, 207us x4)
//  - dt_proj GEMM BK 8 -> 16
//  - chunked 2-pass parallel scan, bf16 MFMA in/out proj (unchanged from R1)
// Shapes: B=4, L=1024, D_MODEL=768, D_INNER=1536, DT_RANK=48, D_STATE=16.
// ---------------------------------------------------------------------------

#define BB 4
#define LL 1024
#define DM 768
#define DI 1536
#define RK 48
#define NS 16
#define CH 16          // scan chunks
#define CLEN 64        // LL / CH
#define XKS 8          // x_proj split-K chunks
#define XKC 192        // 1536 / XKS

typedef __attribute__((ext_vector_type(8))) short bf16x8;
typedef __attribute__((ext_vector_type(4))) float f32x4;

__device__ __forceinline__ float siluf(float x) {
    return x / (1.f + __expf(-x));
}
__device__ __forceinline__ float softplusf(float x) {
    return (x > 20.f) ? x : log1pf(__expf(x));
}
__device__ __forceinline__ unsigned short f2bf(float x) {
    __hip_bfloat16 h = __float2bfloat16(x);
    return *(unsigned short*)&h;
}

// ---------------- LayerNorm: one block per row of 768, bf16 out ------------
__global__ __launch_bounds__(256)
void ln_kernel(const float* __restrict__ h, const float* __restrict__ w,
               const float* __restrict__ bvec, unsigned short* __restrict__ out)
{
    int row = blockIdx.x;                 // 0 .. B*L-1
    const float* x = h + (size_t)row * DM;
    int tid = threadIdx.x;
    float v[3];
    float s = 0.f, s2 = 0.f;
#pragma unroll
    for (int j = 0; j < 3; ++j) {
        v[j] = x[tid + j * 256];
        s += v[j];
        s2 += v[j] * v[j];
    }
#pragma unroll
    for (int off = 32; off > 0; off >>= 1) {
        s += __shfl_down(s, off);
        s2 += __shfl_down(s2, off);
    }
    __shared__ float sw[4], sw2[4], stat[2];
    int wid = tid >> 6;
    if ((tid & 63) == 0) { sw[wid] = s; sw2[wid] = s2; }
    __syncthreads();
    if (tid == 0) {
        float a = sw[0] + sw[1] + sw[2] + sw[3];
        float a2 = sw2[0] + sw2[1] + sw2[2] + sw2[3];
        float mu = a * (1.f / DM);
        float var = a2 * (1.f / DM) - mu * mu;
        stat[0] = mu;
        stat[1] = rsqrtf(var + 1e-5f);
    }
    __syncthreads();
    float mu = stat[0], rs = stat[1];
    unsigned short* o = out + (size_t)row * DM;
#pragma unroll
    for (int j = 0; j < 3; ++j) {
        int i = tid + j * 256;
        o[i] = f2bf((v[j] - mu) * rs * w[i] + bvec[i]);
    }
}

// ---------------- fp32 -> bf16 cast (4 elems / thread) ---------------------
__global__ __launch_bounds__(256)
void cast_kernel(const float* __restrict__ x, unsigned short* __restrict__ y)
{
    int i = (blockIdx.x * 256 + threadIdx.x) * 4;
    float4 v = *(const float4*)(x + i);
    y[i + 0] = f2bf(v.x);
    y[i + 1] = f2bf(v.y);
    y[i + 2] = f2bf(v.z);
    y[i + 3] = f2bf(v.w);
}

// ---------------- bf16 MFMA GEMM: C = A @ B^T (fp32 out) -------------------
__global__ __launch_bounds__(256)
void gemm_mfma_bt(const unsigned short* __restrict__ A, int lda,
                  const unsigned short* __restrict__ B, int ldb,
                  float* __restrict__ C, int ldc, int K)
{
    __shared__ unsigned short As[128 * 32];
    __shared__ unsigned short Bs[128 * 32];
    int tid = threadIdx.x;
    int wave = tid >> 6, lane = tid & 63;
    int wm = wave & 1, wn = wave >> 1;      // 2x2 wave grid
    int quad = lane >> 4, lr = lane & 15;
    int m0 = blockIdx.y * 128, n0 = blockIdx.x * 128;

    f32x4 acc[4][4];
#pragma unroll
    for (int i = 0; i < 4; ++i)
#pragma unroll
        for (int j = 0; j < 4; ++j) acc[i][j] = (f32x4){0.f, 0.f, 0.f, 0.f};

    for (int kt = 0; kt < K; kt += 32) {
#pragma unroll
        for (int i = 0; i < 2; ++i) {
            int idx = tid + i * 256;               // 0..511
            int row = idx >> 2, col = (idx & 3) * 8;
            *(float4*)(&As[row * 32 + col]) =
                *(const float4*)(A + (size_t)(m0 + row) * lda + kt + col);
            *(float4*)(&Bs[row * 32 + col]) =
                *(const float4*)(B + (size_t)(n0 + row) * ldb + kt + col);
        }
        __syncthreads();

        bf16x8 af[4], bf[4];
#pragma unroll
        for (int mt = 0; mt < 4; ++mt)
            af[mt] = *(const bf16x8*)(&As[(wm * 64 + mt * 16 + lr) * 32 + quad * 8]);
#pragma unroll
        for (int nt = 0; nt < 4; ++nt)
            bf[nt] = *(const bf16x8*)(&Bs[(wn * 64 + nt * 16 + lr) * 32 + quad * 8]);
#pragma unroll
        for (int mt = 0; mt < 4; ++mt)
#pragma unroll
            for (int nt = 0; nt < 4; ++nt)
                acc[mt][nt] = __builtin_amdgcn_mfma_f32_16x16x32_bf16(
                    af[mt], bf[nt], acc[mt][nt], 0, 0, 0);
        __syncthreads();
    }

#pragma unroll
    for (int mt = 0; mt < 4; ++mt) {
#pragma unroll
        for (int nt = 0; nt < 4; ++nt) {
#pragma unroll
            for (int e = 0; e < 4; ++e) {
                int m = m0 + wm * 64 + mt * 16 + quad * 4 + e;
                int n = n0 + wn * 64 + nt * 16 + lr;
                C[(size_t)m * ldc + n] = acc[mt][nt][e];
            }
        }
    }
}

// ---------------- fp32 tiled GEMM: C = act(A @ B^T + bias) ------------------
template <int BM, int BN, int BK, int TM, int TN, int ACT>
__global__ __launch_bounds__(256)
void gemm_tn(const float* __restrict__ A, int lda,
             const float* __restrict__ B, int ldb,
             const float* __restrict__ bias,
             float* __restrict__ C, int ldc, int K)
{
    constexpr int TX = BN / TN;
    constexpr int TY = BM / TM;
    static_assert(TX * TY == 256, "thread count must be 256");
    __shared__ float As[BK][BM + 4];
    __shared__ float Bs[BK][BN + 4];

    int tid = threadIdx.x;
    int tx = tid % TX, ty = tid / TX;
    int m0 = blockIdx.y * BM, n0 = blockIdx.x * BN;

    float acc[TM][TN];
#pragma unroll
    for (int i = 0; i < TM; ++i)
#pragma unroll
        for (int j = 0; j < TN; ++j) acc[i][j] = 0.f;

    for (int kt = 0; kt < K; kt += BK) {
#pragma unroll
        for (int i = tid; i < BM * BK; i += 256) {
            int m = i / BK, k = i % BK;
            As[k][m] = A[(size_t)(m0 + m) * lda + kt + k];
        }
#pragma unroll
        for (int i = tid; i < BN * BK; i += 256) {
            int n = i / BK, k = i % BK;
            Bs[k][n] = B[(size_t)(n0 + n) * ldb + kt + k];
        }
        __syncthreads();
#pragma unroll
        for (int kk = 0; kk < BK; ++kk) {
            float a[TM], b[TN];
#pragma unroll
            for (int i = 0; i < TM; ++i) a[i] = As[kk][ty * TM + i];
#pragma unroll
            for (int j = 0; j < TN; ++j) b[j] = Bs[kk][tx * TN + j];
#pragma unroll
            for (int i = 0; i < TM; ++i)
#pragma unroll
                for (int j = 0; j < TN; ++j) acc[i][j] += a[i] * b[j];
        }
        __syncthreads();
    }

#pragma unroll
    for (int i = 0; i < TM; ++i) {
#pragma unroll
        for (int j = 0; j < TN; ++j) {
            int m = m0 + ty * TM + i, n = n0 + tx * TN + j;
            float v = acc[i][j];
            if (ACT == 1) v = softplusf(v + bias[n]);
            C[(size_t)m * ldc + n] = v;
        }
    }
}

// ---------------- x_proj split-K partial GEMM -------------------------------
// part[ks][m][n] = xc[m, ks*192:(ks+1)*192] @ xp_w[n, same].T
// grid (XKS, 64); block 256 = 16x16, each thread 4 rows x 5 cols (col=tx+16j).
__global__ __launch_bounds__(256)
void xproj_partial(const float* __restrict__ A, const float* __restrict__ W,
                   float* __restrict__ part)
{
    __shared__ float As[32][68];
    __shared__ float Ws[32][84];
    int tid = threadIdx.x;
    int tx = tid & 15, ty = tid >> 4;
    int k0 = blockIdx.x * XKC;
    int m0 = blockIdx.y * 64;

    float acc[4][5];
#pragma unroll
    for (int i = 0; i < 4; ++i)
#pragma unroll
        for (int j = 0; j < 5; ++j) acc[i][j] = 0.f;

    for (int kt = 0; kt < XKC; kt += 32) {
        // stage A: 64 rows x 32 k = 512 float4; thread -> 2
#pragma unroll
        for (int i = 0; i < 2; ++i) {
            int idx = tid + i * 256;
            int r = idx >> 3, c4 = (idx & 7) * 4;
            float4 v = *(const float4*)(A + (size_t)(m0 + r) * DI + k0 + kt + c4);
            As[c4 + 0][r] = v.x;
            As[c4 + 1][r] = v.y;
            As[c4 + 2][r] = v.z;
            As[c4 + 3][r] = v.w;
        }
        // stage W: 80 rows x 32 k = 640 float4
        for (int idx = tid; idx < 640; idx += 256) {
            int r = idx >> 3, c4 = (idx & 7) * 4;
            float4 v = *(const float4*)(W + (size_t)r * DI + k0 + kt + c4);
            Ws[c4 + 0][r] = v.x;
            Ws[c4 + 1][r] = v.y;
            Ws[c4 + 2][r] = v.z;
            Ws[c4 + 3][r] = v.w;
        }
        __syncthreads();
#pragma unroll
        for (int kk = 0; kk < 32; ++kk) {
            float a[4], w[5];
#pragma unroll
            for (int i = 0; i < 4; ++i) a[i] = As[kk][ty * 4 + i];
#pragma unroll
            for (int j = 0; j < 5; ++j) w[j] = Ws[kk][tx + 16 * j];
#pragma unroll
            for (int i = 0; i < 4; ++i)
#pragma unroll
                for (int j = 0; j < 5; ++j) acc[i][j] += a[i] * w[j];
        }
        __syncthreads();
    }

    float* p = part + ((size_t)blockIdx.x * BB * LL + m0) * 80;
#pragma unroll
    for (int i = 0; i < 4; ++i)
#pragma unroll
        for (int j = 0; j < 5; ++j)
            p[(size_t)(ty * 4 + i) * 80 + tx + 16 * j] = acc[i][j];
}

// ---------------- x_proj reduce: xdbl = sum over XKS partials ---------------
__global__ __launch_bounds__(256)
void xproj_reduce(const float* __restrict__ part, float* __restrict__ xdbl)
{
    int i = blockIdx.x * 256 + threadIdx.x;     // over 4096*80
    float s = 0.f;
#pragma unroll
    for (int ks = 0; ks < XKS; ++ks)
        s += part[(size_t)ks * BB * LL * 80 + i];
    xdbl[i] = s;
}

// ---------------- causal depthwise conv (k=4) + silu ------------------------
__global__ __launch_bounds__(256)
void conv_silu_kernel(const float* __restrict__ xz, const float* __restrict__ w,
                      const float* __restrict__ bias, float* __restrict__ xc,
                      int rev)
{
    int gid = blockIdx.x * 256 + threadIdx.x;   // over B*L*DI
    int d = gid % DI;
    int bt = gid / DI;
    int t = bt % LL;
    int b = bt / LL;
    float acc = bias[d];
#pragma unroll
    for (int i = 0; i < 4; ++i) {
        int tt = t - 3 + i;
        if (tt >= 0) {
            int st = rev ? (LL - 1 - tt) : tt;
            acc += xz[((size_t)(b * LL + st)) * (2 * DI) + d] * w[d * 4 + i];
        }
    }
    xc[gid] = siluf(acc);
}

// ---------------- selective scan, pass 1: per-chunk (p, q) ------------------
__global__ __launch_bounds__(256)
void scan_p1(const float* __restrict__ dt, const float* __restrict__ u,
             const float* __restrict__ xdbl, const float* __restrict__ A_log,
             float2* __restrict__ PQ)
{
    int gid = blockIdx.x * 256 + threadIdx.x;   // over B*DI*NS
    int c = blockIdx.y;
    int n = gid & 15;
    int dch = gid >> 4;
    int d = dch % DI, b = dch / DI;

    float Av = -expf(A_log[d * NS + n]);
    size_t base = ((size_t)b * LL + c * CLEN) * DI + d;
    size_t xb = ((size_t)b * LL + c * CLEN) * 80;

    float p = 1.f, q = 0.f;
    for (int t = 0; t < CLEN; ++t) {
        float dtv = dt[base + (size_t)t * DI];
        float uv = u[base + (size_t)t * DI];
        float Bv = xdbl[xb + t * 80 + 48 + n];
        float dA = __expf(dtv * Av);
        q = dA * q + (dtv * uv) * Bv;
        p *= dA;
    }
    PQ[(size_t)gid * CH + c] = make_float2(p, q);
}

// ---------------- selective scan, pass 2: replay with true h0 ---------------
__global__ __launch_bounds__(256)
void scan_p2(const float* __restrict__ dt, const float* __restrict__ u,
             const float* __restrict__ xdbl, const float* __restrict__ A_log,
             const float* __restrict__ Dp, const float2* __restrict__ PQ,
             float* __restrict__ g, int rev)
{
    int gid = blockIdx.x * 256 + threadIdx.x;
    int c = blockIdx.y;
    int n = gid & 15;
    int dch = gid >> 4;
    int d = dch % DI, b = dch / DI;

    float Av = -expf(A_log[d * NS + n]);
    float Dpv = Dp[d];

    float h = 0.f;
    const float2* pq = PQ + (size_t)gid * CH;
    for (int cc = 0; cc < c; ++cc) {
        float2 s = pq[cc];
        h = s.x * h + s.y;
    }

    size_t base = ((size_t)b * LL + c * CLEN) * DI + d;
    size_t xb = ((size_t)b * LL + c * CLEN) * 80;

    for (int t = 0; t < CLEN; ++t) {
        float dtv = dt[base + (size_t)t * DI];
        float uv = u[base + (size_t)t * DI];
        float Bv = xdbl[xb + t * 80 + 48 + n];
        float Cv = xdbl[xb + t * 80 + 64 + n];
        float dA = __expf(dtv * Av);
        h = dA * h + (dtv * uv) * Bv;
        float yp = h * Cv;
        yp += __shfl_xor(yp, 8);
        yp += __shfl_xor(yp, 4);
        yp += __shfl_xor(yp, 2);
        yp += __shfl_xor(yp, 1);
        if (n == 0) {
            int tt = c * CLEN + t;
            int ot = rev ? (LL - 1 - tt) : tt;
            size_t oi = ((size_t)b * LL + ot) * DI + d;
            float val = yp + uv * Dpv;
            if (rev) g[oi] += val;
            else     g[oi] = val;
        }
    }
}

// ---------------- gate: gb = bf16(g * silu(z)) ------------------------------
__global__ __launch_bounds__(256)
void gate_kernel(const float* __restrict__ g, const float* __restrict__ xz,
                 unsigned short* __restrict__ gb)
{
    int gid = blockIdx.x * 256 + threadIdx.x;   // over B*L*DI
    int d = gid % DI;
    int bt = gid / DI;
    float z = xz[(size_t)bt * (2 * DI) + DI + d];
    gb[gid] = f2bf(g[gid] * siluf(z));
}

// ---------------------------------------------------------------------------
extern "C" void kernel_launch(void* const* d_in, const int* in_sizes, int n_in,
                              void* d_out, int out_size, void* d_ws, size_t ws_size,
                              hipStream_t stream)
{
    const float* h_r        = (const float*)d_in[0];
    const float* h_i        = (const float*)d_in[1];
    const float* ln_w       = (const float*)d_in[2];
    const float* ln_b       = (const float*)d_in[3];
    const float* in_w       = (const float*)d_in[4];
    const float* conv_w     = (const float*)d_in[5];
    const float* conv_bias  = (const float*)d_in[6];
    const float* xp_w       = (const float*)d_in[7];
    const float* dtp_w      = (const float*)d_in[8];
    const float* dtp_bias   = (const float*)d_in[9];
    const float* A_log      = (const float*)d_in[10];
    const float* D_p        = (const float*)d_in[11];
    const float* conv_w_b   = (const float*)d_in[12];
    const float* conv_bias_b= (const float*)d_in[13];
    const float* xp_w_b     = (const float*)d_in[14];
    const float* dtp_w_b    = (const float*)d_in[15];
    const float* dtp_bias_b = (const float*)d_in[16];
    const float* A_b_log    = (const float*)d_in[17];
    const float* D_b        = (const float*)d_in[18];
    const float* out_w      = (const float*)d_in[19];
    float* out = (float*)d_out;

    // workspace layout
    float*  ws   = (float*)d_ws;
    float*  g    = ws;                              // 6,291,456 f
    float*  xz   = g + (size_t)BB * LL * DI;        // 12,582,912 f
    float*  xc   = xz + (size_t)BB * LL * 2 * DI;   // 6,291,456 f
    float*  dtb  = xc + (size_t)BB * LL * DI;       // 6,291,456 f
    float*  xdbl = dtb + (size_t)BB * LL * DI;      // 327,680 f
    float2* PQ   = (float2*)(xdbl + (size_t)BB * LL * 80);        // 1,572,864 f2
    unsigned short* gb  = (unsigned short*)(PQ + (size_t)BB * DI * NS * CH); // 6,291,456 us
    unsigned short* hnb = gb;          // alias: dead before gate writes gb
    float* xpart = (float*)gb;         // alias: XKS*4096*80 f = 10.5MB <= 12.6MB,
                                       // dead before gate, live only conv->reduce
    unsigned short* wbi = gb + (size_t)BB * LL * DI;   // 2,359,296 us
    unsigned short* wbo = wbi + (size_t)2 * DI * DM;   // 1,179,648 us

    const size_t out_stride = (size_t)BB * LL * DM;

    for (int br = 0; br < 2; ++br) {
        const float* h = br ? h_i : h_r;

        ln_kernel<<<BB * LL, 256, 0, stream>>>(h, ln_w + br * DM, ln_b + br * DM, hnb);

        cast_kernel<<<(2 * DI * DM) / 1024, 256, 0, stream>>>(
            in_w + (size_t)br * 2 * DI * DM, wbi);
        cast_kernel<<<(DM * DI) / 1024, 256, 0, stream>>>(
            out_w + (size_t)br * DM * DI, wbo);

        // xz = hn @ in_w.T   [4096 x 3072], K=768  (bf16 MFMA)
        gemm_mfma_bt<<<dim3((2 * DI) / 128, (BB * LL) / 128), 256, 0, stream>>>(
            hnb, DM, wbi, DM, xz, 2 * DI, DM);

        for (int dir = 0; dir < 2; ++dir) {
            const float* cw = (dir ? conv_w_b : conv_w) + (size_t)br * DI * 4;
            const float* cb = (dir ? conv_bias_b : conv_bias) + (size_t)br * DI;
            const float* xw = (dir ? xp_w_b : xp_w) + (size_t)br * 80 * DI;
            const float* dw = (dir ? dtp_w_b : dtp_w) + (size_t)br * DI * RK;
            const float* db = (dir ? dtp_bias_b : dtp_bias) + (size_t)br * DI;
            const float* al = (dir ? A_b_log : A_log) + (size_t)br * DI * NS;
            const float* dp = (dir ? D_b : D_p) + (size_t)br * DI;

            conv_silu_kernel<<<(BB * LL * DI) / 256, 256, 0, stream>>>(xz, cw, cb, xc, dir);

            // xdbl = xc @ xp_w.T  [4096 x 80], K=1536 (fp32 split-K + reduce)
            xproj_partial<<<dim3(XKS, (BB * LL) / 64), 256, 0, stream>>>(xc, xw, xpart);
            xproj_reduce<<<(BB * LL * 80) / 256, 256, 0, stream>>>(xpart, xdbl);

            // dt = softplus(xdbl[:, :48] @ dtp_w.T + bias)  [4096 x 1536], K=48
            gemm_tn<128, 128, 16, 8, 8, 1><<<dim3(DI / 128, (BB * LL) / 128), 256, 0, stream>>>(
                xdbl, 80, dw, RK, db, dtb, DI, RK);

            // chunked parallel scan
            scan_p1<<<dim3((BB * DI * NS) / 256, CH), 256, 0, stream>>>(
                dtb, xc, xdbl, al, PQ);
            scan_p2<<<dim3((BB * DI * NS) / 256, CH), 256, 0, stream>>>(
                dtb, xc, xdbl, al, dp, PQ, g, dir);
        }

        gate_kernel<<<(BB * LL * DI) / 256, 256, 0, stream>>>(g, xz, gb);

        // out = g @ out_w.T   [4096 x 768], K=1536  (bf16 MFMA)
        gemm_mfma_bt<<<dim3(DM / 128, (BB * LL) / 128), 256, 0, stream>>>(
            gb, DI, wbo, DI, out + br * out_stride, DM, DI);
    }
}

// Round 4
// 1143.287 us; speedup vs baseline: 4.1130x; 1.3840x over previous
//
#include <hip/hip_runtime.h>
#include <hip/hip_bf16.h>
#include <math.h>

// ---------------------------------------------------------------------------
// MambaBlock (bimamba v2). Round 3:
//  - scan rewritten: one lane per (b,d), 16 n-states in registers, no
//    shuffles; B/C staged in LDS (broadcast reads); chunk prefix composed by
//    tiny scan_mid kernel (PQ transposed [c][gid] for coalescing).
//  - everything else unchanged from R2.
// Shapes: B=4, L=1024, D_MODEL=768, D_INNER=1536, DT_RANK=48, D_STATE=16.
// ---------------------------------------------------------------------------

#define BB 4
#define LL 1024
#define DM 768
#define DI 1536
#define RK 48
#define NS 16
#define CH 16          // scan chunks
#define CLEN 64        // LL / CH
#define DB6 (DI / 256) // d-blocks per batch in scan
#define XKS 8          // x_proj split-K chunks
#define XKC 192        // 1536 / XKS

typedef __attribute__((ext_vector_type(8))) short bf16x8;
typedef __attribute__((ext_vector_type(4))) float f32x4;

__device__ __forceinline__ float siluf(float x) {
    return x / (1.f + __expf(-x));
}
__device__ __forceinline__ float softplusf(float x) {
    return (x > 20.f) ? x : log1pf(__expf(x));
}
__device__ __forceinline__ unsigned short f2bf(float x) {
    __hip_bfloat16 h = __float2bfloat16(x);
    return *(unsigned short*)&h;
}

// ---------------- LayerNorm: one block per row of 768, bf16 out ------------
__global__ __launch_bounds__(256)
void ln_kernel(const float* __restrict__ h, const float* __restrict__ w,
               const float* __restrict__ bvec, unsigned short* __restrict__ out)
{
    int row = blockIdx.x;                 // 0 .. B*L-1
    const float* x = h + (size_t)row * DM;
    int tid = threadIdx.x;
    float v[3];
    float s = 0.f, s2 = 0.f;
#pragma unroll
    for (int j = 0; j < 3; ++j) {
        v[j] = x[tid + j * 256];
        s += v[j];
        s2 += v[j] * v[j];
    }
#pragma unroll
    for (int off = 32; off > 0; off >>= 1) {
        s += __shfl_down(s, off);
        s2 += __shfl_down(s2, off);
    }
    __shared__ float sw[4], sw2[4], stat[2];
    int wid = tid >> 6;
    if ((tid & 63) == 0) { sw[wid] = s; sw2[wid] = s2; }
    __syncthreads();
    if (tid == 0) {
        float a = sw[0] + sw[1] + sw[2] + sw[3];
        float a2 = sw2[0] + sw2[1] + sw2[2] + sw2[3];
        float mu = a * (1.f / DM);
        float var = a2 * (1.f / DM) - mu * mu;
        stat[0] = mu;
        stat[1] = rsqrtf(var + 1e-5f);
    }
    __syncthreads();
    float mu = stat[0], rs = stat[1];
    unsigned short* o = out + (size_t)row * DM;
#pragma unroll
    for (int j = 0; j < 3; ++j) {
        int i = tid + j * 256;
        o[i] = f2bf((v[j] - mu) * rs * w[i] + bvec[i]);
    }
}

// ---------------- fp32 -> bf16 cast (4 elems / thread) ---------------------
__global__ __launch_bounds__(256)
void cast_kernel(const float* __restrict__ x, unsigned short* __restrict__ y)
{
    int i = (blockIdx.x * 256 + threadIdx.x) * 4;
    float4 v = *(const float4*)(x + i);
    y[i + 0] = f2bf(v.x);
    y[i + 1] = f2bf(v.y);
    y[i + 2] = f2bf(v.z);
    y[i + 3] = f2bf(v.w);
}

// ---------------- bf16 MFMA GEMM: C = A @ B^T (fp32 out) -------------------
__global__ __launch_bounds__(256)
void gemm_mfma_bt(const unsigned short* __restrict__ A, int lda,
                  const unsigned short* __restrict__ B, int ldb,
                  float* __restrict__ C, int ldc, int K)
{
    __shared__ unsigned short As[128 * 32];
    __shared__ unsigned short Bs[128 * 32];
    int tid = threadIdx.x;
    int wave = tid >> 6, lane = tid & 63;
    int wm = wave & 1, wn = wave >> 1;      // 2x2 wave grid
    int quad = lane >> 4, lr = lane & 15;
    int m0 = blockIdx.y * 128, n0 = blockIdx.x * 128;

    f32x4 acc[4][4];
#pragma unroll
    for (int i = 0; i < 4; ++i)
#pragma unroll
        for (int j = 0; j < 4; ++j) acc[i][j] = (f32x4){0.f, 0.f, 0.f, 0.f};

    for (int kt = 0; kt < K; kt += 32) {
#pragma unroll
        for (int i = 0; i < 2; ++i) {
            int idx = tid + i * 256;               // 0..511
            int row = idx >> 2, col = (idx & 3) * 8;
            *(float4*)(&As[row * 32 + col]) =
                *(const float4*)(A + (size_t)(m0 + row) * lda + kt + col);
            *(float4*)(&Bs[row * 32 + col]) =
                *(const float4*)(B + (size_t)(n0 + row) * ldb + kt + col);
        }
        __syncthreads();

        bf16x8 af[4], bf[4];
#pragma unroll
        for (int mt = 0; mt < 4; ++mt)
            af[mt] = *(const bf16x8*)(&As[(wm * 64 + mt * 16 + lr) * 32 + quad * 8]);
#pragma unroll
        for (int nt = 0; nt < 4; ++nt)
            bf[nt] = *(const bf16x8*)(&Bs[(wn * 64 + nt * 16 + lr) * 32 + quad * 8]);
#pragma unroll
        for (int mt = 0; mt < 4; ++mt)
#pragma unroll
            for (int nt = 0; nt < 4; ++nt)
                acc[mt][nt] = __builtin_amdgcn_mfma_f32_16x16x32_bf16(
                    af[mt], bf[nt], acc[mt][nt], 0, 0, 0);
        __syncthreads();
    }

#pragma unroll
    for (int mt = 0; mt < 4; ++mt) {
#pragma unroll
        for (int nt = 0; nt < 4; ++nt) {
#pragma unroll
            for (int e = 0; e < 4; ++e) {
                int m = m0 + wm * 64 + mt * 16 + quad * 4 + e;
                int n = n0 + wn * 64 + nt * 16 + lr;
                C[(size_t)m * ldc + n] = acc[mt][nt][e];
            }
        }
    }
}

// ---------------- fp32 tiled GEMM: C = act(A @ B^T + bias) ------------------
template <int BM, int BN, int BK, int TM, int TN, int ACT>
__global__ __launch_bounds__(256)
void gemm_tn(const float* __restrict__ A, int lda,
             const float* __restrict__ B, int ldb,
             const float* __restrict__ bias,
             float* __restrict__ C, int ldc, int K)
{
    constexpr int TX = BN / TN;
    constexpr int TY = BM / TM;
    static_assert(TX * TY == 256, "thread count must be 256");
    __shared__ float As[BK][BM + 4];
    __shared__ float Bs[BK][BN + 4];

    int tid = threadIdx.x;
    int tx = tid % TX, ty = tid / TX;
    int m0 = blockIdx.y * BM, n0 = blockIdx.x * BN;

    float acc[TM][TN];
#pragma unroll
    for (int i = 0; i < TM; ++i)
#pragma unroll
        for (int j = 0; j < TN; ++j) acc[i][j] = 0.f;

    for (int kt = 0; kt < K; kt += BK) {
#pragma unroll
        for (int i = tid; i < BM * BK; i += 256) {
            int m = i / BK, k = i % BK;
            As[k][m] = A[(size_t)(m0 + m) * lda + kt + k];
        }
#pragma unroll
        for (int i = tid; i < BN * BK; i += 256) {
            int n = i / BK, k = i % BK;
            Bs[k][n] = B[(size_t)(n0 + n) * ldb + kt + k];
        }
        __syncthreads();
#pragma unroll
        for (int kk = 0; kk < BK; ++kk) {
            float a[TM], b[TN];
#pragma unroll
            for (int i = 0; i < TM; ++i) a[i] = As[kk][ty * TM + i];
#pragma unroll
            for (int j = 0; j < TN; ++j) b[j] = Bs[kk][tx * TN + j];
#pragma unroll
            for (int i = 0; i < TM; ++i)
#pragma unroll
                for (int j = 0; j < TN; ++j) acc[i][j] += a[i] * b[j];
        }
        __syncthreads();
    }

#pragma unroll
    for (int i = 0; i < TM; ++i) {
#pragma unroll
        for (int j = 0; j < TN; ++j) {
            int m = m0 + ty * TM + i, n = n0 + tx * TN + j;
            float v = acc[i][j];
            if (ACT == 1) v = softplusf(v + bias[n]);
            C[(size_t)m * ldc + n] = v;
        }
    }
}

// ---------------- x_proj split-K partial GEMM -------------------------------
__global__ __launch_bounds__(256)
void xproj_partial(const float* __restrict__ A, const float* __restrict__ W,
                   float* __restrict__ part)
{
    __shared__ float As[32][68];
    __shared__ float Ws[32][84];
    int tid = threadIdx.x;
    int tx = tid & 15, ty = tid >> 4;
    int k0 = blockIdx.x * XKC;
    int m0 = blockIdx.y * 64;

    float acc[4][5];
#pragma unroll
    for (int i = 0; i < 4; ++i)
#pragma unroll
        for (int j = 0; j < 5; ++j) acc[i][j] = 0.f;

    for (int kt = 0; kt < XKC; kt += 32) {
#pragma unroll
        for (int i = 0; i < 2; ++i) {
            int idx = tid + i * 256;
            int r = idx >> 3, c4 = (idx & 7) * 4;
            float4 v = *(const float4*)(A + (size_t)(m0 + r) * DI + k0 + kt + c4);
            As[c4 + 0][r] = v.x;
            As[c4 + 1][r] = v.y;
            As[c4 + 2][r] = v.z;
            As[c4 + 3][r] = v.w;
        }
        for (int idx = tid; idx < 640; idx += 256) {
            int r = idx >> 3, c4 = (idx & 7) * 4;
            float4 v = *(const float4*)(W + (size_t)r * DI + k0 + kt + c4);
            Ws[c4 + 0][r] = v.x;
            Ws[c4 + 1][r] = v.y;
            Ws[c4 + 2][r] = v.z;
            Ws[c4 + 3][r] = v.w;
        }
        __syncthreads();
#pragma unroll
        for (int kk = 0; kk < 32; ++kk) {
            float a[4], w[5];
#pragma unroll
            for (int i = 0; i < 4; ++i) a[i] = As[kk][ty * 4 + i];
#pragma unroll
            for (int j = 0; j < 5; ++j) w[j] = Ws[kk][tx + 16 * j];
#pragma unroll
            for (int i = 0; i < 4; ++i)
#pragma unroll
                for (int j = 0; j < 5; ++j) acc[i][j] += a[i] * w[j];
        }
        __syncthreads();
    }

    float* p = part + ((size_t)blockIdx.x * BB * LL + m0) * 80;
#pragma unroll
    for (int i = 0; i < 4; ++i)
#pragma unroll
        for (int j = 0; j < 5; ++j)
            p[(size_t)(ty * 4 + i) * 80 + tx + 16 * j] = acc[i][j];
}

// ---------------- x_proj reduce: xdbl = sum over XKS partials ---------------
__global__ __launch_bounds__(256)
void xproj_reduce(const float* __restrict__ part, float* __restrict__ xdbl)
{
    int i = blockIdx.x * 256 + threadIdx.x;     // over 4096*80
    float s = 0.f;
#pragma unroll
    for (int ks = 0; ks < XKS; ++ks)
        s += part[(size_t)ks * BB * LL * 80 + i];
    xdbl[i] = s;
}

// ---------------- causal depthwise conv (k=4) + silu ------------------------
__global__ __launch_bounds__(256)
void conv_silu_kernel(const float* __restrict__ xz, const float* __restrict__ w,
                      const float* __restrict__ bias, float* __restrict__ xc,
                      int rev)
{
    int gid = blockIdx.x * 256 + threadIdx.x;   // over B*L*DI
    int d = gid % DI;
    int bt = gid / DI;
    int t = bt % LL;
    int b = bt / LL;
    float acc = bias[d];
#pragma unroll
    for (int i = 0; i < 4; ++i) {
        int tt = t - 3 + i;
        if (tt >= 0) {
            int st = rev ? (LL - 1 - tt) : tt;
            acc += xz[((size_t)(b * LL + st)) * (2 * DI) + d] * w[d * 4 + i];
        }
    }
    xc[gid] = siluf(acc);
}

// ---------------- selective scan, pass 1: per-chunk (p, q) ------------------
// one lane per (b,d); 16 n-states in registers; B staged in LDS.
// PQ layout: [c][(b*DI+d)*NS + n] float2.
__global__ __launch_bounds__(256)
void scan_p1(const float* __restrict__ dt, const float* __restrict__ u,
             const float* __restrict__ xdbl, const float* __restrict__ A_log,
             float2* __restrict__ PQ)
{
    int c = blockIdx.y;
    int b = blockIdx.x / DB6;
    int d = (blockIdx.x % DB6) * 256 + threadIdx.x;

    float Av[16];
    {
        const float4* a4 = (const float4*)(A_log + (size_t)d * NS);
#pragma unroll
        for (int j = 0; j < 4; ++j) {
            float4 v = a4[j];
            Av[4 * j + 0] = -expf(v.x);
            Av[4 * j + 1] = -expf(v.y);
            Av[4 * j + 2] = -expf(v.z);
            Av[4 * j + 3] = -expf(v.w);
        }
    }

    __shared__ float Bs[CLEN * NS];
    for (int i = threadIdx.x; i < CLEN * NS; i += 256) {
        int t = i >> 4, n = i & 15;
        Bs[i] = xdbl[((size_t)(b * LL + c * CLEN + t)) * 80 + 48 + n];
    }
    __syncthreads();

    float q[16];
#pragma unroll
    for (int n = 0; n < 16; ++n) q[n] = 0.f;
    float dtsum = 0.f;

    size_t base = ((size_t)b * LL + c * CLEN) * DI + d;
    // prefetch ring, depth 2
    float dt0 = dt[base], u0 = u[base];
    float dt1 = dt[base + DI], u1 = u[base + DI];
    for (int t = 0; t < CLEN; ++t) {
        float dt2 = 0.f, u2 = 0.f;
        if (t + 2 < CLEN) {
            dt2 = dt[base + (size_t)(t + 2) * DI];
            u2 = u[base + (size_t)(t + 2) * DI];
        }
        float du = dt0 * u0;
        dtsum += dt0;
        const float4* b4 = (const float4*)(Bs + t * NS);
#pragma unroll
        for (int j = 0; j < 4; ++j) {
            float4 Bv = b4[j];
            q[4 * j + 0] = __expf(dt0 * Av[4 * j + 0]) * q[4 * j + 0] + du * Bv.x;
            q[4 * j + 1] = __expf(dt0 * Av[4 * j + 1]) * q[4 * j + 1] + du * Bv.y;
            q[4 * j + 2] = __expf(dt0 * Av[4 * j + 2]) * q[4 * j + 2] + du * Bv.z;
            q[4 * j + 3] = __expf(dt0 * Av[4 * j + 3]) * q[4 * j + 3] + du * Bv.w;
        }
        dt0 = dt1; u0 = u1; dt1 = dt2; u1 = u2;
    }

    float2* o = PQ + (size_t)c * (BB * DI * NS) + (size_t)(b * DI + d) * NS;
#pragma unroll
    for (int n = 0; n < 16; ++n)
        o[n] = make_float2(__expf(dtsum * Av[n]), q[n]);
}

// ---------------- scan mid: compose chunk prefixes -> H0 --------------------
__global__ __launch_bounds__(256)
void scan_mid(const float2* __restrict__ PQ, float* __restrict__ H0)
{
    int gid = blockIdx.x * 256 + threadIdx.x;   // over BB*DI*NS
    float h = 0.f;
#pragma unroll
    for (int c = 0; c < CH; ++c) {
        H0[(size_t)c * (BB * DI * NS) + gid] = h;
        float2 s = PQ[(size_t)c * (BB * DI * NS) + gid];
        h = s.x * h + s.y;
    }
}

// ---------------- selective scan, pass 2: replay with true h0 ---------------
__global__ __launch_bounds__(256)
void scan_p2(const float* __restrict__ dt, const float* __restrict__ u,
             const float* __restrict__ xdbl, const float* __restrict__ A_log,
             const float* __restrict__ Dp, const float* __restrict__ H0,
             float* __restrict__ g, int rev)
{
    int c = blockIdx.y;
    int b = blockIdx.x / DB6;
    int d = (blockIdx.x % DB6) * 256 + threadIdx.x;

    float Av[16];
    {
        const float4* a4 = (const float4*)(A_log + (size_t)d * NS);
#pragma unroll
        for (int j = 0; j < 4; ++j) {
            float4 v = a4[j];
            Av[4 * j + 0] = -expf(v.x);
            Av[4 * j + 1] = -expf(v.y);
            Av[4 * j + 2] = -expf(v.z);
            Av[4 * j + 3] = -expf(v.w);
        }
    }
    float h[16];
    {
        const float4* h4 = (const float4*)(H0 + (size_t)c * (BB * DI * NS)
                                           + (size_t)(b * DI + d) * NS);
#pragma unroll
        for (int j = 0; j < 4; ++j) {
            float4 v = h4[j];
            h[4 * j + 0] = v.x; h[4 * j + 1] = v.y;
            h[4 * j + 2] = v.z; h[4 * j + 3] = v.w;
        }
    }
    float Dpv = Dp[d];

    __shared__ float Bs[CLEN * NS];
    __shared__ float Cs[CLEN * NS];
    for (int i = threadIdx.x; i < CLEN * NS; i += 256) {
        int t = i >> 4, n = i & 15;
        size_t src = ((size_t)(b * LL + c * CLEN + t)) * 80;
        Bs[i] = xdbl[src + 48 + n];
        Cs[i] = xdbl[src + 64 + n];
    }
    __syncthreads();

    size_t base = ((size_t)b * LL + c * CLEN) * DI + d;
    float dt0 = dt[base], u0 = u[base];
    float dt1 = dt[base + DI], u1 = u[base + DI];
    for (int t = 0; t < CLEN; ++t) {
        float dt2 = 0.f, u2 = 0.f;
        if (t + 2 < CLEN) {
            dt2 = dt[base + (size_t)(t + 2) * DI];
            u2 = u[base + (size_t)(t + 2) * DI];
        }
        float du = dt0 * u0;
        float y = 0.f;
        const float4* b4 = (const float4*)(Bs + t * NS);
        const float4* c4 = (const float4*)(Cs + t * NS);
#pragma unroll
        for (int j = 0; j < 4; ++j) {
            float4 Bv = b4[j];
            float4 Cv = c4[j];
            h[4 * j + 0] = __expf(dt0 * Av[4 * j + 0]) * h[4 * j + 0] + du * Bv.x;
            h[4 * j + 1] = __expf(dt0 * Av[4 * j + 1]) * h[4 * j + 1] + du * Bv.y;
            h[4 * j + 2] = __expf(dt0 * Av[4 * j + 2]) * h[4 * j + 2] + du * Bv.z;
            h[4 * j + 3] = __expf(dt0 * Av[4 * j + 3]) * h[4 * j + 3] + du * Bv.w;
            y += h[4 * j + 0] * Cv.x + h[4 * j + 1] * Cv.y
               + h[4 * j + 2] * Cv.z + h[4 * j + 3] * Cv.w;
        }
        int tt = c * CLEN + t;
        int ot = rev ? (LL - 1 - tt) : tt;
        size_t oi = ((size_t)b * LL + ot) * DI + d;
        float val = y + u0 * Dpv;
        if (rev) g[oi] += val;
        else     g[oi] = val;
        dt0 = dt1; u0 = u1; dt1 = dt2; u1 = u2;
    }
}

// ---------------- gate: gb = bf16(g * silu(z)) ------------------------------
__global__ __launch_bounds__(256)
void gate_kernel(const float* __restrict__ g, const float* __restrict__ xz,
                 unsigned short* __restrict__ gb)
{
    int gid = blockIdx.x * 256 + threadIdx.x;   // over B*L*DI
    int d = gid % DI;
    int bt = gid / DI;
    float z = xz[(size_t)bt * (2 * DI) + DI + d];
    gb[gid] = f2bf(g[gid] * siluf(z));
}

// ---------------------------------------------------------------------------
extern "C" void kernel_launch(void* const* d_in, const int* in_sizes, int n_in,
                              void* d_out, int out_size, void* d_ws, size_t ws_size,
                              hipStream_t stream)
{
    const float* h_r        = (const float*)d_in[0];
    const float* h_i        = (const float*)d_in[1];
    const float* ln_w       = (const float*)d_in[2];
    const float* ln_b       = (const float*)d_in[3];
    const float* in_w       = (const float*)d_in[4];
    const float* conv_w     = (const float*)d_in[5];
    const float* conv_bias  = (const float*)d_in[6];
    const float* xp_w       = (const float*)d_in[7];
    const float* dtp_w      = (const float*)d_in[8];
    const float* dtp_bias   = (const float*)d_in[9];
    const float* A_log      = (const float*)d_in[10];
    const float* D_p        = (const float*)d_in[11];
    const float* conv_w_b   = (const float*)d_in[12];
    const float* conv_bias_b= (const float*)d_in[13];
    const float* xp_w_b     = (const float*)d_in[14];
    const float* dtp_w_b    = (const float*)d_in[15];
    const float* dtp_bias_b = (const float*)d_in[16];
    const float* A_b_log    = (const float*)d_in[17];
    const float* D_b        = (const float*)d_in[18];
    const float* out_w      = (const float*)d_in[19];
    float* out = (float*)d_out;

    // workspace layout
    float*  ws   = (float*)d_ws;
    float*  g    = ws;                              // 6,291,456 f
    float*  xz   = g + (size_t)BB * LL * DI;        // 12,582,912 f
    float*  xc   = xz + (size_t)BB * LL * 2 * DI;   // 6,291,456 f
    float*  dtb  = xc + (size_t)BB * LL * DI;       // 6,291,456 f
    float*  xdbl = dtb + (size_t)BB * LL * DI;      // 327,680 f
    float2* PQ   = (float2*)(xdbl + (size_t)BB * LL * 80);        // [CH][98304] f2
    unsigned short* gb  = (unsigned short*)(PQ + (size_t)CH * BB * DI * NS);
    unsigned short* hnb = gb;          // alias: dead before gate writes gb
    float* xpart = (float*)gb;         // alias: live only conv->reduce
    float* H0    = (float*)gb;         // alias: live only scan_mid->scan_p2 (6.3MB)
    unsigned short* wbi = gb + (size_t)BB * LL * DI;   // 2,359,296 us
    unsigned short* wbo = wbi + (size_t)2 * DI * DM;   // 1,179,648 us

    const size_t out_stride = (size_t)BB * LL * DM;

    for (int br = 0; br < 2; ++br) {
        const float* h = br ? h_i : h_r;

        ln_kernel<<<BB * LL, 256, 0, stream>>>(h, ln_w + br * DM, ln_b + br * DM, hnb);

        cast_kernel<<<(2 * DI * DM) / 1024, 256, 0, stream>>>(
            in_w + (size_t)br * 2 * DI * DM, wbi);
        cast_kernel<<<(DM * DI) / 1024, 256, 0, stream>>>(
            out_w + (size_t)br * DM * DI, wbo);

        // xz = hn @ in_w.T   [4096 x 3072], K=768  (bf16 MFMA)
        gemm_mfma_bt<<<dim3((2 * DI) / 128, (BB * LL) / 128), 256, 0, stream>>>(
            hnb, DM, wbi, DM, xz, 2 * DI, DM);

        for (int dir = 0; dir < 2; ++dir) {
            const float* cw = (dir ? conv_w_b : conv_w) + (size_t)br * DI * 4;
            const float* cb = (dir ? conv_bias_b : conv_bias) + (size_t)br * DI;
            const float* xw = (dir ? xp_w_b : xp_w) + (size_t)br * 80 * DI;
            const float* dw = (dir ? dtp_w_b : dtp_w) + (size_t)br * DI * RK;
            const float* db = (dir ? dtp_bias_b : dtp_bias) + (size_t)br * DI;
            const float* al = (dir ? A_b_log : A_log) + (size_t)br * DI * NS;
            const float* dp = (dir ? D_b : D_p) + (size_t)br * DI;

            conv_silu_kernel<<<(BB * LL * DI) / 256, 256, 0, stream>>>(xz, cw, cb, xc, dir);

            // xdbl = xc @ xp_w.T  [4096 x 80], K=1536 (fp32 split-K + reduce)
            xproj_partial<<<dim3(XKS, (BB * LL) / 64), 256, 0, stream>>>(xc, xw, xpart);
            xproj_reduce<<<(BB * LL * 80) / 256, 256, 0, stream>>>(xpart, xdbl);

            // dt = softplus(xdbl[:, :48] @ dtp_w.T + bias)  [4096 x 1536], K=48
            gemm_tn<128, 128, 16, 8, 8, 1><<<dim3(DI / 128, (BB * LL) / 128), 256, 0, stream>>>(
                xdbl, 80, dw, RK, db, dtb, DI, RK);

            // chunked parallel scan (register-state version)
            scan_p1<<<dim3(BB * DB6, CH), 256, 0, stream>>>(dtb, xc, xdbl, al, PQ);
            scan_mid<<<(BB * DI * NS) / 256, 256, 0, stream>>>(PQ, H0);
            scan_p2<<<dim3(BB * DB6, CH), 256, 0, stream>>>(
                dtb, xc, xdbl, al, dp, H0, g, dir);
        }

        gate_kernel<<<(BB * LL * DI) / 256, 256, 0, stream>>>(g, xz, gb);

        // out = g @ out_w.T   [4096 x 768], K=1536  (bf16 MFMA)
        gemm_mfma_bt<<<dim3(DM / 128, (BB * LL) / 128), 256, 0, stream>>>(
            gb, DI, wbo, DI, out + br * out_stride, DM, DI);
    }
}

// Round 5
// 1047.936 us; speedup vs baseline: 4.4872x; 1.0910x over previous
//
#include <hip/hip_runtime.h>
#include <hip/hip_bf16.h>
#include <math.h>

// ---------------------------------------------------------------------------
// MambaBlock (bimamba v2). Round 4:
//  - scan: CH 16->32 (768 blocks, 12 waves/CU), prefetch ring depth 8,
//    A = -exp(A_log) precomputed by aexp_kernel
//  - gemm_mfma_bt: async global_load_lds (width 16) staging
// Shapes: B=4, L=1024, D_MODEL=768, D_INNER=1536, DT_RANK=48, D_STATE=16.
// ---------------------------------------------------------------------------

#define BB 4
#define LL 1024
#define DM 768
#define DI 1536
#define RK 48
#define NS 16
#define CH 32          // scan chunks
#define CLEN 32        // LL / CH
#define DB6 (DI / 256) // d-blocks per batch in scan
#define XKS 8          // x_proj split-K chunks
#define XKC 192        // 1536 / XKS

typedef __attribute__((ext_vector_type(8))) short bf16x8;
typedef __attribute__((ext_vector_type(4))) float f32x4;

__device__ __forceinline__ float siluf(float x) {
    return x / (1.f + __expf(-x));
}
__device__ __forceinline__ float softplusf(float x) {
    return (x > 20.f) ? x : log1pf(__expf(x));
}
__device__ __forceinline__ unsigned short f2bf(float x) {
    __hip_bfloat16 h = __float2bfloat16(x);
    return *(unsigned short*)&h;
}
__device__ __forceinline__ void async_cp16(const void* g, void* l) {
    __builtin_amdgcn_global_load_lds(
        (const __attribute__((address_space(1))) void*)g,
        (__attribute__((address_space(3))) void*)l, 16, 0, 0);
}

// ---------------- LayerNorm: one block per row of 768, bf16 out ------------
__global__ __launch_bounds__(256)
void ln_kernel(const float* __restrict__ h, const float* __restrict__ w,
               const float* __restrict__ bvec, unsigned short* __restrict__ out)
{
    int row = blockIdx.x;                 // 0 .. B*L-1
    const float* x = h + (size_t)row * DM;
    int tid = threadIdx.x;
    float v[3];
    float s = 0.f, s2 = 0.f;
#pragma unroll
    for (int j = 0; j < 3; ++j) {
        v[j] = x[tid + j * 256];
        s += v[j];
        s2 += v[j] * v[j];
    }
#pragma unroll
    for (int off = 32; off > 0; off >>= 1) {
        s += __shfl_down(s, off);
        s2 += __shfl_down(s2, off);
    }
    __shared__ float sw[4], sw2[4], stat[2];
    int wid = tid >> 6;
    if ((tid & 63) == 0) { sw[wid] = s; sw2[wid] = s2; }
    __syncthreads();
    if (tid == 0) {
        float a = sw[0] + sw[1] + sw[2] + sw[3];
        float a2 = sw2[0] + sw2[1] + sw2[2] + sw2[3];
        float mu = a * (1.f / DM);
        float var = a2 * (1.f / DM) - mu * mu;
        stat[0] = mu;
        stat[1] = rsqrtf(var + 1e-5f);
    }
    __syncthreads();
    float mu = stat[0], rs = stat[1];
    unsigned short* o = out + (size_t)row * DM;
#pragma unroll
    for (int j = 0; j < 3; ++j) {
        int i = tid + j * 256;
        o[i] = f2bf((v[j] - mu) * rs * w[i] + bvec[i]);
    }
}

// ---------------- fp32 -> bf16 cast (4 elems / thread) ---------------------
__global__ __launch_bounds__(256)
void cast_kernel(const float* __restrict__ x, unsigned short* __restrict__ y)
{
    int i = (blockIdx.x * 256 + threadIdx.x) * 4;
    float4 v = *(const float4*)(x + i);
    y[i + 0] = f2bf(v.x);
    y[i + 1] = f2bf(v.y);
    y[i + 2] = f2bf(v.z);
    y[i + 3] = f2bf(v.w);
}

// ---------------- Avm = -exp(A_log) ----------------------------------------
__global__ __launch_bounds__(256)
void aexp_kernel(const float* __restrict__ A_log, float* __restrict__ Avm)
{
    int i = blockIdx.x * 256 + threadIdx.x;     // over DI*NS
    Avm[i] = -expf(A_log[i]);
}

// ---------------- bf16 MFMA GEMM: C = A @ B^T (fp32 out) -------------------
// async global->LDS staging (16B/lane), 128x128 tile, BK=32.
__global__ __launch_bounds__(256)
void gemm_mfma_bt(const unsigned short* __restrict__ A, int lda,
                  const unsigned short* __restrict__ B, int ldb,
                  float* __restrict__ C, int ldc, int K)
{
    __shared__ unsigned short As[128 * 32];
    __shared__ unsigned short Bs[128 * 32];
    int tid = threadIdx.x;
    int wave = tid >> 6, lane = tid & 63;
    int wm = wave & 1, wn = wave >> 1;      // 2x2 wave grid
    int quad = lane >> 4, lr = lane & 15;
    int m0 = blockIdx.y * 128, n0 = blockIdx.x * 128;

    f32x4 acc[4][4];
#pragma unroll
    for (int i = 0; i < 4; ++i)
#pragma unroll
        for (int j = 0; j < 4; ++j) acc[i][j] = (f32x4){0.f, 0.f, 0.f, 0.f};

    for (int kt = 0; kt < K; kt += 32) {
        // stage 128x32 of A and B: LDS dest = wave-uniform base + lane*16
#pragma unroll
        for (int i = 0; i < 2; ++i) {
            int idx = tid + i * 256;               // 0..511
            int row = idx >> 2, col = (idx & 3) * 8;
            async_cp16(A + (size_t)(m0 + row) * lda + kt + col, &As[idx * 8]);
            async_cp16(B + (size_t)(n0 + row) * ldb + kt + col, &Bs[idx * 8]);
        }
        __syncthreads();

        bf16x8 af[4], bf[4];
#pragma unroll
        for (int mt = 0; mt < 4; ++mt)
            af[mt] = *(const bf16x8*)(&As[(wm * 64 + mt * 16 + lr) * 32 + quad * 8]);
#pragma unroll
        for (int nt = 0; nt < 4; ++nt)
            bf[nt] = *(const bf16x8*)(&Bs[(wn * 64 + nt * 16 + lr) * 32 + quad * 8]);
#pragma unroll
        for (int mt = 0; mt < 4; ++mt)
#pragma unroll
            for (int nt = 0; nt < 4; ++nt)
                acc[mt][nt] = __builtin_amdgcn_mfma_f32_16x16x32_bf16(
                    af[mt], bf[nt], acc[mt][nt], 0, 0, 0);
        __syncthreads();
    }

#pragma unroll
    for (int mt = 0; mt < 4; ++mt) {
#pragma unroll
        for (int nt = 0; nt < 4; ++nt) {
#pragma unroll
            for (int e = 0; e < 4; ++e) {
                int m = m0 + wm * 64 + mt * 16 + quad * 4 + e;
                int n = n0 + wn * 64 + nt * 16 + lr;
                C[(size_t)m * ldc + n] = acc[mt][nt][e];
            }
        }
    }
}

// ---------------- fp32 tiled GEMM: C = act(A @ B^T + bias) ------------------
template <int BM, int BN, int BK, int TM, int TN, int ACT>
__global__ __launch_bounds__(256)
void gemm_tn(const float* __restrict__ A, int lda,
             const float* __restrict__ B, int ldb,
             const float* __restrict__ bias,
             float* __restrict__ C, int ldc, int K)
{
    constexpr int TX = BN / TN;
    constexpr int TY = BM / TM;
    static_assert(TX * TY == 256, "thread count must be 256");
    __shared__ float As[BK][BM + 4];
    __shared__ float Bs[BK][BN + 4];

    int tid = threadIdx.x;
    int tx = tid % TX, ty = tid / TX;
    int m0 = blockIdx.y * BM, n0 = blockIdx.x * BN;

    float acc[TM][TN];
#pragma unroll
    for (int i = 0; i < TM; ++i)
#pragma unroll
        for (int j = 0; j < TN; ++j) acc[i][j] = 0.f;

    for (int kt = 0; kt < K; kt += BK) {
#pragma unroll
        for (int i = tid; i < BM * BK; i += 256) {
            int m = i / BK, k = i % BK;
            As[k][m] = A[(size_t)(m0 + m) * lda + kt + k];
        }
#pragma unroll
        for (int i = tid; i < BN * BK; i += 256) {
            int n = i / BK, k = i % BK;
            Bs[k][n] = B[(size_t)(n0 + n) * ldb + kt + k];
        }
        __syncthreads();
#pragma unroll
        for (int kk = 0; kk < BK; ++kk) {
            float a[TM], b[TN];
#pragma unroll
            for (int i = 0; i < TM; ++i) a[i] = As[kk][ty * TM + i];
#pragma unroll
            for (int j = 0; j < TN; ++j) b[j] = Bs[kk][tx * TN + j];
#pragma unroll
            for (int i = 0; i < TM; ++i)
#pragma unroll
                for (int j = 0; j < TN; ++j) acc[i][j] += a[i] * b[j];
        }
        __syncthreads();
    }

#pragma unroll
    for (int i = 0; i < TM; ++i) {
#pragma unroll
        for (int j = 0; j < TN; ++j) {
            int m = m0 + ty * TM + i, n = n0 + tx * TN + j;
            float v = acc[i][j];
            if (ACT == 1) v = softplusf(v + bias[n]);
            C[(size_t)m * ldc + n] = v;
        }
    }
}

// ---------------- x_proj split-K partial GEMM -------------------------------
__global__ __launch_bounds__(256)
void xproj_partial(const float* __restrict__ A, const float* __restrict__ W,
                   float* __restrict__ part)
{
    __shared__ float As[32][68];
    __shared__ float Ws[32][84];
    int tid = threadIdx.x;
    int tx = tid & 15, ty = tid >> 4;
    int k0 = blockIdx.x * XKC;
    int m0 = blockIdx.y * 64;

    float acc[4][5];
#pragma unroll
    for (int i = 0; i < 4; ++i)
#pragma unroll
        for (int j = 0; j < 5; ++j) acc[i][j] = 0.f;

    for (int kt = 0; kt < XKC; kt += 32) {
#pragma unroll
        for (int i = 0; i < 2; ++i) {
            int idx = tid + i * 256;
            int r = idx >> 3, c4 = (idx & 7) * 4;
            float4 v = *(const float4*)(A + (size_t)(m0 + r) * DI + k0 + kt + c4);
            As[c4 + 0][r] = v.x;
            As[c4 + 1][r] = v.y;
            As[c4 + 2][r] = v.z;
            As[c4 + 3][r] = v.w;
        }
        for (int idx = tid; idx < 640; idx += 256) {
            int r = idx >> 3, c4 = (idx & 7) * 4;
            float4 v = *(const float4*)(W + (size_t)r * DI + k0 + kt + c4);
            Ws[c4 + 0][r] = v.x;
            Ws[c4 + 1][r] = v.y;
            Ws[c4 + 2][r] = v.z;
            Ws[c4 + 3][r] = v.w;
        }
        __syncthreads();
#pragma unroll
        for (int kk = 0; kk < 32; ++kk) {
            float a[4], w[5];
#pragma unroll
            for (int i = 0; i < 4; ++i) a[i] = As[kk][ty * 4 + i];
#pragma unroll
            for (int j = 0; j < 5; ++j) w[j] = Ws[kk][tx + 16 * j];
#pragma unroll
            for (int i = 0; i < 4; ++i)
#pragma unroll
                for (int j = 0; j < 5; ++j) acc[i][j] += a[i] * w[j];
        }
        __syncthreads();
    }

    float* p = part + ((size_t)blockIdx.x * BB * LL + m0) * 80;
#pragma unroll
    for (int i = 0; i < 4; ++i)
#pragma unroll
        for (int j = 0; j < 5; ++j)
            p[(size_t)(ty * 4 + i) * 80 + tx + 16 * j] = acc[i][j];
}

// ---------------- x_proj reduce: xdbl = sum over XKS partials ---------------
__global__ __launch_bounds__(256)
void xproj_reduce(const float* __restrict__ part, float* __restrict__ xdbl)
{
    int i = blockIdx.x * 256 + threadIdx.x;     // over 4096*80
    float s = 0.f;
#pragma unroll
    for (int ks = 0; ks < XKS; ++ks)
        s += part[(size_t)ks * BB * LL * 80 + i];
    xdbl[i] = s;
}

// ---------------- causal depthwise conv (k=4) + silu ------------------------
__global__ __launch_bounds__(256)
void conv_silu_kernel(const float* __restrict__ xz, const float* __restrict__ w,
                      const float* __restrict__ bias, float* __restrict__ xc,
                      int rev)
{
    int gid = blockIdx.x * 256 + threadIdx.x;   // over B*L*DI
    int d = gid % DI;
    int bt = gid / DI;
    int t = bt % LL;
    int b = bt / LL;
    float acc = bias[d];
#pragma unroll
    for (int i = 0; i < 4; ++i) {
        int tt = t - 3 + i;
        if (tt >= 0) {
            int st = rev ? (LL - 1 - tt) : tt;
            acc += xz[((size_t)(b * LL + st)) * (2 * DI) + d] * w[d * 4 + i];
        }
    }
    xc[gid] = siluf(acc);
}

// ---------------- selective scan, pass 1: per-chunk (p, q) ------------------
// one lane per (b,d); 16 n-states in registers; prefetch ring depth 8.
// PQ layout: [c][(b*DI+d)*NS + n] float2.
__global__ __launch_bounds__(256)
void scan_p1(const float* __restrict__ dt, const float* __restrict__ u,
             const float* __restrict__ xdbl, const float* __restrict__ Avm,
             float2* __restrict__ PQ)
{
    int c = blockIdx.y;
    int b = blockIdx.x / DB6;
    int d = (blockIdx.x % DB6) * 256 + threadIdx.x;

    float Av[16];
    {
        const float4* a4 = (const float4*)(Avm + (size_t)d * NS);
#pragma unroll
        for (int j = 0; j < 4; ++j) {
            float4 v = a4[j];
            Av[4 * j + 0] = v.x; Av[4 * j + 1] = v.y;
            Av[4 * j + 2] = v.z; Av[4 * j + 3] = v.w;
        }
    }

    __shared__ float Bs[CLEN * NS];
    for (int i = threadIdx.x; i < CLEN * NS; i += 256) {
        int t = i >> 4, n = i & 15;
        Bs[i] = xdbl[((size_t)(b * LL + c * CLEN + t)) * 80 + 48 + n];
    }
    __syncthreads();

    float q[16];
#pragma unroll
    for (int n = 0; n < 16; ++n) q[n] = 0.f;
    float dtsum = 0.f;

    size_t base = ((size_t)b * LL + c * CLEN) * DI + d;
    float dtr[8], ur[8];
#pragma unroll
    for (int i = 0; i < 8; ++i) {
        dtr[i] = dt[base + (size_t)i * DI];
        ur[i]  = u[base + (size_t)i * DI];
    }
#pragma unroll
    for (int t = 0; t < CLEN; ++t) {
        float dtv = dtr[t & 7], uv = ur[t & 7];
        if (t + 8 < CLEN) {
            dtr[t & 7] = dt[base + (size_t)(t + 8) * DI];
            ur[t & 7]  = u[base + (size_t)(t + 8) * DI];
        }
        float du = dtv * uv;
        dtsum += dtv;
        const float4* b4 = (const float4*)(Bs + t * NS);
#pragma unroll
        for (int j = 0; j < 4; ++j) {
            float4 Bv = b4[j];
            q[4 * j + 0] = __expf(dtv * Av[4 * j + 0]) * q[4 * j + 0] + du * Bv.x;
            q[4 * j + 1] = __expf(dtv * Av[4 * j + 1]) * q[4 * j + 1] + du * Bv.y;
            q[4 * j + 2] = __expf(dtv * Av[4 * j + 2]) * q[4 * j + 2] + du * Bv.z;
            q[4 * j + 3] = __expf(dtv * Av[4 * j + 3]) * q[4 * j + 3] + du * Bv.w;
        }
    }

    float2* o = PQ + (size_t)c * (BB * DI * NS) + (size_t)(b * DI + d) * NS;
#pragma unroll
    for (int n = 0; n < 16; ++n)
        o[n] = make_float2(__expf(dtsum * Av[n]), q[n]);
}

// ---------------- scan mid: compose chunk prefixes -> H0 --------------------
__global__ __launch_bounds__(256)
void scan_mid(const float2* __restrict__ PQ, float* __restrict__ H0)
{
    int gid = blockIdx.x * 256 + threadIdx.x;   // over BB*DI*NS
    float h = 0.f;
#pragma unroll
    for (int c = 0; c < CH; ++c) {
        H0[(size_t)c * (BB * DI * NS) + gid] = h;
        float2 s = PQ[(size_t)c * (BB * DI * NS) + gid];
        h = s.x * h + s.y;
    }
}

// ---------------- selective scan, pass 2: replay with true h0 ---------------
__global__ __launch_bounds__(256)
void scan_p2(const float* __restrict__ dt, const float* __restrict__ u,
             const float* __restrict__ xdbl, const float* __restrict__ Avm,
             const float* __restrict__ Dp, const float* __restrict__ H0,
             float* __restrict__ g, int rev)
{
    int c = blockIdx.y;
    int b = blockIdx.x / DB6;
    int d = (blockIdx.x % DB6) * 256 + threadIdx.x;

    float Av[16];
    {
        const float4* a4 = (const float4*)(Avm + (size_t)d * NS);
#pragma unroll
        for (int j = 0; j < 4; ++j) {
            float4 v = a4[j];
            Av[4 * j + 0] = v.x; Av[4 * j + 1] = v.y;
            Av[4 * j + 2] = v.z; Av[4 * j + 3] = v.w;
        }
    }
    float h[16];
    {
        const float4* h4 = (const float4*)(H0 + (size_t)c * (BB * DI * NS)
                                           + (size_t)(b * DI + d) * NS);
#pragma unroll
        for (int j = 0; j < 4; ++j) {
            float4 v = h4[j];
            h[4 * j + 0] = v.x; h[4 * j + 1] = v.y;
            h[4 * j + 2] = v.z; h[4 * j + 3] = v.w;
        }
    }
    float Dpv = Dp[d];

    __shared__ float Bs[CLEN * NS];
    __shared__ float Cs[CLEN * NS];
    for (int i = threadIdx.x; i < CLEN * NS; i += 256) {
        int t = i >> 4, n = i & 15;
        size_t src = ((size_t)(b * LL + c * CLEN + t)) * 80;
        Bs[i] = xdbl[src + 48 + n];
        Cs[i] = xdbl[src + 64 + n];
    }
    __syncthreads();

    size_t base = ((size_t)b * LL + c * CLEN) * DI + d;
    float dtr[8], ur[8];
#pragma unroll
    for (int i = 0; i < 8; ++i) {
        dtr[i] = dt[base + (size_t)i * DI];
        ur[i]  = u[base + (size_t)i * DI];
    }
#pragma unroll
    for (int t = 0; t < CLEN; ++t) {
        float dtv = dtr[t & 7], uv = ur[t & 7];
        if (t + 8 < CLEN) {
            dtr[t & 7] = dt[base + (size_t)(t + 8) * DI];
            ur[t & 7]  = u[base + (size_t)(t + 8) * DI];
        }
        float du = dtv * uv;
        float y = 0.f;
        const float4* b4 = (const float4*)(Bs + t * NS);
        const float4* c4 = (const float4*)(Cs + t * NS);
#pragma unroll
        for (int j = 0; j < 4; ++j) {
            float4 Bv = b4[j];
            float4 Cv = c4[j];
            h[4 * j + 0] = __expf(dtv * Av[4 * j + 0]) * h[4 * j + 0] + du * Bv.x;
            h[4 * j + 1] = __expf(dtv * Av[4 * j + 1]) * h[4 * j + 1] + du * Bv.y;
            h[4 * j + 2] = __expf(dtv * Av[4 * j + 2]) * h[4 * j + 2] + du * Bv.z;
            h[4 * j + 3] = __expf(dtv * Av[4 * j + 3]) * h[4 * j + 3] + du * Bv.w;
            y += h[4 * j + 0] * Cv.x + h[4 * j + 1] * Cv.y
               + h[4 * j + 2] * Cv.z + h[4 * j + 3] * Cv.w;
        }
        int tt = c * CLEN + t;
        int ot = rev ? (LL - 1 - tt) : tt;
        size_t oi = ((size_t)b * LL + ot) * DI + d;
        float val = y + uv * Dpv;
        if (rev) g[oi] += val;
        else     g[oi] = val;
    }
}

// ---------------- gate: gb = bf16(g * silu(z)) ------------------------------
__global__ __launch_bounds__(256)
void gate_kernel(const float* __restrict__ g, const float* __restrict__ xz,
                 unsigned short* __restrict__ gb)
{
    int gid = blockIdx.x * 256 + threadIdx.x;   // over B*L*DI
    int d = gid % DI;
    int bt = gid / DI;
    float z = xz[(size_t)bt * (2 * DI) + DI + d];
    gb[gid] = f2bf(g[gid] * siluf(z));
}

// ---------------------------------------------------------------------------
extern "C" void kernel_launch(void* const* d_in, const int* in_sizes, int n_in,
                              void* d_out, int out_size, void* d_ws, size_t ws_size,
                              hipStream_t stream)
{
    const float* h_r        = (const float*)d_in[0];
    const float* h_i        = (const float*)d_in[1];
    const float* ln_w       = (const float*)d_in[2];
    const float* ln_b       = (const float*)d_in[3];
    const float* in_w       = (const float*)d_in[4];
    const float* conv_w     = (const float*)d_in[5];
    const float* conv_bias  = (const float*)d_in[6];
    const float* xp_w       = (const float*)d_in[7];
    const float* dtp_w      = (const float*)d_in[8];
    const float* dtp_bias   = (const float*)d_in[9];
    const float* A_log      = (const float*)d_in[10];
    const float* D_p        = (const float*)d_in[11];
    const float* conv_w_b   = (const float*)d_in[12];
    const float* conv_bias_b= (const float*)d_in[13];
    const float* xp_w_b     = (const float*)d_in[14];
    const float* dtp_w_b    = (const float*)d_in[15];
    const float* dtp_bias_b = (const float*)d_in[16];
    const float* A_b_log    = (const float*)d_in[17];
    const float* D_b        = (const float*)d_in[18];
    const float* out_w      = (const float*)d_in[19];
    float* out = (float*)d_out;

    // workspace layout (floats)
    float*  ws   = (float*)d_ws;
    float*  g    = ws;                              // 6,291,456 f
    float*  xz   = g + (size_t)BB * LL * DI;        // 12,582,912 f
    float*  xc   = xz + (size_t)BB * LL * 2 * DI;   // 6,291,456 f
    float*  dtb  = xc + (size_t)BB * LL * DI;       // 6,291,456 f
    float*  xdbl = dtb + (size_t)BB * LL * DI;      // 327,680 f
    float*  Avm  = xdbl + (size_t)BB * LL * 80;     // 24,576 f
    float2* PQ   = (float2*)(Avm + DI * NS);        // CH*98304 f2 = 25.2 MB
    unsigned short* gb  = (unsigned short*)(PQ + (size_t)CH * BB * DI * NS);
    unsigned short* hnb = gb;          // alias: dead before gate writes gb
    float* xpart = (float*)gb;         // alias: live only conv->reduce (10.5MB)
    float* H0    = (float*)gb;         // alias: live only scan_mid->scan_p2
                                       //        (CH*98304 f = 12.58MB = gb size)
    unsigned short* wbi = gb + (size_t)BB * LL * DI;   // 2,359,296 us
    unsigned short* wbo = wbi + (size_t)2 * DI * DM;   // 1,179,648 us

    const size_t out_stride = (size_t)BB * LL * DM;

    for (int br = 0; br < 2; ++br) {
        const float* h = br ? h_i : h_r;

        ln_kernel<<<BB * LL, 256, 0, stream>>>(h, ln_w + br * DM, ln_b + br * DM, hnb);

        cast_kernel<<<(2 * DI * DM) / 1024, 256, 0, stream>>>(
            in_w + (size_t)br * 2 * DI * DM, wbi);
        cast_kernel<<<(DM * DI) / 1024, 256, 0, stream>>>(
            out_w + (size_t)br * DM * DI, wbo);

        // xz = hn @ in_w.T   [4096 x 3072], K=768  (bf16 MFMA)
        gemm_mfma_bt<<<dim3((2 * DI) / 128, (BB * LL) / 128), 256, 0, stream>>>(
            hnb, DM, wbi, DM, xz, 2 * DI, DM);

        for (int dir = 0; dir < 2; ++dir) {
            const float* cw = (dir ? conv_w_b : conv_w) + (size_t)br * DI * 4;
            const float* cb = (dir ? conv_bias_b : conv_bias) + (size_t)br * DI;
            const float* xw = (dir ? xp_w_b : xp_w) + (size_t)br * 80 * DI;
            const float* dw = (dir ? dtp_w_b : dtp_w) + (size_t)br * DI * RK;
            const float* db = (dir ? dtp_bias_b : dtp_bias) + (size_t)br * DI;
            const float* al = (dir ? A_b_log : A_log) + (size_t)br * DI * NS;
            const float* dp = (dir ? D_b : D_p) + (size_t)br * DI;

            conv_silu_kernel<<<(BB * LL * DI) / 256, 256, 0, stream>>>(xz, cw, cb, xc, dir);

            // xdbl = xc @ xp_w.T  [4096 x 80], K=1536 (fp32 split-K + reduce)
            xproj_partial<<<dim3(XKS, (BB * LL) / 64), 256, 0, stream>>>(xc, xw, xpart);
            xproj_reduce<<<(BB * LL * 80) / 256, 256, 0, stream>>>(xpart, xdbl);

            // dt = softplus(xdbl[:, :48] @ dtp_w.T + bias)  [4096 x 1536], K=48
            gemm_tn<128, 128, 16, 8, 8, 1><<<dim3(DI / 128, (BB * LL) / 128), 256, 0, stream>>>(
                xdbl, 80, dw, RK, db, dtb, DI, RK);

            // chunked parallel scan
            aexp_kernel<<<(DI * NS) / 256, 256, 0, stream>>>(al, Avm);
            scan_p1<<<dim3(BB * DB6, CH), 256, 0, stream>>>(dtb, xc, xdbl, Avm, PQ);
            scan_mid<<<(BB * DI * NS) / 256, 256, 0, stream>>>(PQ, H0);
            scan_p2<<<dim3(BB * DB6, CH), 256, 0, stream>>>(
                dtb, xc, xdbl, Avm, dp, H0, g, dir);
        }

        gate_kernel<<<(BB * LL * DI) / 256, 256, 0, stream>>>(g, xz, gb);

        // out = g @ out_w.T   [4096 x 768], K=1536  (bf16 MFMA)
        gemm_mfma_bt<<<dim3(DM / 128, (BB * LL) / 128), 256, 0, stream>>>(
            gb, DI, wbo, DI, out + br * out_stride, DM, DI);
    }
}